// Round 17
// baseline (205.651 us; speedup 1.0000x reference)
//
#include <hip/hip_runtime.h>
#include <hip/hip_bf16.h>
#include <stdint.h>

#define D_MODEL 1024
#define D_STATE 16
#define D_CONV  4
#define D_INNER 2048
#define BATCH   2
#define SEQLEN  2048
#define NROWS   (BATCH*SEQLEN)     // 4096
#define BCD_LD  36                 // padded leading dim for bcd (33 used)
#define NCHUNK  64
#define CHUNKLEN (SEQLEN/NCHUNK)   // 32
#define KS2     16                 // K-splits for GEMM2 (chunk = 128)
#define L2E 1.44269504088896340f

typedef __attribute__((ext_vector_type(8))) short   short8;
typedef __attribute__((ext_vector_type(4))) float   f32x4;

__device__ __forceinline__ uint16_t f2bf(float f) {        // RNE f32->bf16
    uint32_t u = __float_as_uint(f);
    return (uint16_t)((u + 0x7FFFu + ((u >> 16) & 1u)) >> 16);
}
__device__ __forceinline__ float bf2f(uint16_t h) {
    return __uint_as_float(((uint32_t)h) << 16);
}
__device__ __forceinline__ uint32_t pack2bf(float lo, float hi) {
    return (uint32_t)f2bf(lo) | ((uint32_t)f2bf(hi) << 16);
}
__device__ __forceinline__ void gload16(const uint16_t* g, uint16_t* l) {
    __builtin_amdgcn_global_load_lds(
        (const __attribute__((address_space(1))) void*)g,
        (__attribute__((address_space(3))) void*)l, 16, 0, 0);
}
__device__ __forceinline__ void gload16f(const float* g, float* l) {
    __builtin_amdgcn_global_load_lds(
        (const __attribute__((address_space(1))) void*)g,
        (__attribute__((address_space(3))) void*)l, 16, 0, 0);
}
__device__ __forceinline__ float softplus_f(float v) {
    return fmaxf(v, 0.f) + __logf(1.f + __expf(-fabsf(v)));
}
__device__ __forceinline__ float silu_f(float v) {
    return v / (1.f + __expf(-v));
}
__device__ __forceinline__ short8 pack8(const float4 lo, const float4 hi) {
    short8 r;
    r[0] = (short)f2bf(lo.x); r[1] = (short)f2bf(lo.y);
    r[2] = (short)f2bf(lo.z); r[3] = (short)f2bf(lo.w);
    r[4] = (short)f2bf(hi.x); r[5] = (short)f2bf(hi.y);
    r[6] = (short)f2bf(hi.z); r[7] = (short)f2bf(hi.w);
    return r;
}

// ---------- fused input prep: kcvt | ktrans(W_in) | ktrans(W_out) | kwxt ----------
__global__ void kprep0(const float* __restrict__ x, uint16_t* __restrict__ xb,
                       const float* __restrict__ W_in, uint16_t* __restrict__ Wb,
                       const float* __restrict__ W_out, uint16_t* __restrict__ Wob,
                       const float* __restrict__ Wx, float* __restrict__ Wxt) {
    __shared__ float tile[32][33];
    const int blk = blockIdx.x;
    const int tid = threadIdx.x;
    if (blk < 4096) {                          // ---- cvt x -> bf16 (1M float4s)
        const int T = blk * 256 + tid;
        const float4 v = *(const float4*)&x[(size_t)T * 4];
        ushort4 o;
        o.x = f2bf(v.x); o.y = f2bf(v.y); o.z = f2bf(v.z); o.w = f2bf(v.w);
        *(ushort4*)&xb[(size_t)T * 4] = o;
    } else if (blk < 8192) {                   // ---- W_in [1024][4096] -> Wb [4096][1024]
        const int bb = blk - 4096;
        const int n0 = (bb & 127) * 32, k0 = (bb >> 7) * 32;
        const int tx = tid & 31, ty = tid >> 5;
#pragma unroll
        for (int i = 0; i < 4; ++i)
            tile[ty + i * 8][tx] = W_in[(size_t)(k0 + ty + i * 8) * 4096 + n0 + tx];
        __syncthreads();
#pragma unroll
        for (int i = 0; i < 4; ++i)
            Wb[(size_t)(n0 + ty + i * 8) * 1024 + k0 + tx] = f2bf(tile[tx][ty + i * 8]);
    } else if (blk < 10240) {                  // ---- W_out [2048][1024] -> Wob [1024][2048]
        const int bb = blk - 8192;
        const int n0 = (bb & 31) * 32, k0 = (bb >> 5) * 32;
        const int tx = tid & 31, ty = tid >> 5;
#pragma unroll
        for (int i = 0; i < 4; ++i)
            tile[ty + i * 8][tx] = W_out[(size_t)(k0 + ty + i * 8) * 1024 + n0 + tx];
        __syncthreads();
#pragma unroll
        for (int i = 0; i < 4; ++i)
            Wob[(size_t)(n0 + ty + i * 8) * 2048 + k0 + tx] = f2bf(tile[tx][ty + i * 8]);
    } else {                                   // ---- Wxt[64][2048] = W_x^T zero-padded
        const int T = (blk - 10240) * 256 + tid;
        const int j = T >> 11, k = T & 2047;
        Wxt[T] = (j < 33) ? Wx[(size_t)k * 33 + j] : 0.f;
    }
}

// ---------- GEMM1: 256x256 block, 8 waves (128x64 wave tile), 4-buf vmcnt(8) ----------
// LDS 128 KB (4 bufs x (A 16KB + B 16KB)), prefetch 3 K-tiles, bf16 C out.
template<int KDIM, int GXL>
__global__ __launch_bounds__(512) void kgemm256d(const uint16_t* __restrict__ A,
                                                 const uint16_t* __restrict__ B,
                                                 uint16_t* __restrict__ C, const int ldc) {
    __shared__ uint16_t As[4][256 * 32];   // 4 x 16 KB
    __shared__ uint16_t Bs[4][256 * 32];   // 4 x 16 KB
    const int t = threadIdx.x;          // 0..511
    const int w = t >> 6, lane = t & 63;
    int wg = blockIdx.y * (1 << GXL) + blockIdx.x;
    wg = (wg & 7) * ((gridDim.x * gridDim.y) >> 3) + (wg >> 3);   // bijective XCD swizzle
    const int m0 = (wg >> GXL) * 256, n0 = (wg & ((1 << GXL) - 1)) * 256;
    const int wm = (w >> 2) * 128, wn = (w & 3) * 64;
    f32x4 acc[8][4] = {};

    const int srow = t >> 2;                              // 0..127
    const int scol = ((t & 3) ^ ((t >> 3) & 3)) * 8;      // pre-swizzled source slot
    const uint16_t* ga0 = A + (size_t)(m0 + srow) * KDIM + scol;
    const uint16_t* ga1 = A + (size_t)(m0 + 128 + srow) * KDIM + scol;
    const uint16_t* gb0 = B + (size_t)(n0 + srow) * KDIM + scol;
    const uint16_t* gb1 = B + (size_t)(n0 + 128 + srow) * KDIM + scol;

    const int fr = lane & 15, fg = (lane >> 4) * 8;
    const int psl = (((fg >> 3) ^ ((fr >> 1) & 3)) << 3);

    auto stage = [&](int buf, int ko) {
        gload16(ga0 + ko, &As[buf][w * 512]);
        gload16(ga1 + ko, &As[buf][4096 + w * 512]);
        gload16(gb0 + ko, &Bs[buf][w * 512]);
        gload16(gb1 + ko, &Bs[buf][4096 + w * 512]);
    };

    constexpr int KT = KDIM / 32;       // 32 K-tiles
    stage(0, 0);
    stage(1, 32);
    stage(2, 64);                       // 12 loads in flight (3 tiles deep)
    int cur = 0;
    for (int kt = 0; kt < KT; ++kt) {
        // retire tile kt's 4 loads; keep up to 8 (tiles kt+1, kt+2) in flight
        if (kt + 2 < KT)      asm volatile("s_waitcnt vmcnt(8)" ::: "memory");
        else if (kt + 1 < KT) asm volatile("s_waitcnt vmcnt(4)" ::: "memory");
        else                  asm volatile("s_waitcnt vmcnt(0)" ::: "memory");
        asm volatile("s_barrier" ::: "memory");      // buffer kt fully landed block-wide
        if (kt + 3 < KT) stage((kt + 3) & 3, (kt + 3) * 32);  // overwrites buf (kt-1)&3
        short8 a[8], b[4];
#pragma unroll
        for (int i = 0; i < 8; ++i)
            a[i] = *(const short8*)&As[cur][(wm + i * 16 + fr) * 32 + psl];
#pragma unroll
        for (int j = 0; j < 4; ++j)
            b[j] = *(const short8*)&Bs[cur][(wn + j * 16 + fr) * 32 + psl];
        __builtin_amdgcn_s_setprio(1);
#pragma unroll
        for (int i = 0; i < 8; ++i)
#pragma unroll
            for (int j = 0; j < 4; ++j)
                acc[i][j] = __builtin_amdgcn_mfma_f32_16x16x32_bf16(a[i], b[j], acc[i][j], 0, 0, 0);
        __builtin_amdgcn_s_setprio(0);
        cur = (cur + 1) & 3;
    }
    const int cr = (lane >> 4) * 4, cc = lane & 15;
#pragma unroll
    for (int i = 0; i < 8; ++i)
#pragma unroll
        for (int j = 0; j < 4; ++j)
#pragma unroll
            for (int r = 0; r < 4; ++r)
                C[(size_t)(m0 + wm + i * 16 + cr + r) * ldc + (n0 + wn + j * 16 + cc)] =
                    f2bf(acc[i][j][r]);
}

// ---------- GEMM3: 64x128 tile, 3-buf counted-vmcnt pipeline, f32 C ----------
template<int KDIM, int GXL>
__global__ __launch_bounds__(256) void kgemm64(const uint16_t* __restrict__ A,
                                               const uint16_t* __restrict__ B,
                                               float* __restrict__ C, const int ldc) {
    __shared__ uint16_t As[3][64 * 32];      // 3 x 4 KB
    __shared__ uint16_t Bsh[3][128 * 32];    // 3 x 8 KB  (36 KB total)
    const int t = threadIdx.x;
    const int w = t >> 6, lane = t & 63;
    int wg = blockIdx.y * (1 << GXL) + blockIdx.x;
    wg = (wg & 7) * ((gridDim.x * gridDim.y) >> 3) + (wg >> 3);
    const int m0 = (wg >> GXL) * 64, n0 = (wg & ((1 << GXL) - 1)) * 128;
    const int wm = (w >> 1) * 32, wn = (w & 1) * 64;
    f32x4 acc[2][4] = {};

    const int srow = t >> 2;
    const int scol = ((t & 3) ^ ((t >> 3) & 3)) * 8;
    const uint16_t* ga0 = A + (size_t)(m0 + srow) * KDIM + scol;
    const uint16_t* gb0 = B + (size_t)(n0 + srow) * KDIM + scol;
    const uint16_t* gb1 = B + (size_t)(n0 + 64 + srow) * KDIM + scol;

    const int fr = lane & 15, fg = (lane >> 4) * 8;
    const int psl = (((fg >> 3) ^ ((fr >> 1) & 3)) << 3);

    auto stage = [&](int buf, int ko) {
        gload16(ga0 + ko, &As[buf][w * 512]);
        gload16(gb0 + ko, &Bsh[buf][w * 512]);
        gload16(gb1 + ko, &Bsh[buf][2048 + w * 512]);
    };

    constexpr int KT = KDIM / 32;
    stage(0, 0);
    stage(1, 32);
    int cur = 0;
    for (int kt = 0; kt < KT; ++kt) {
        if (kt + 1 < KT) asm volatile("s_waitcnt vmcnt(3)" ::: "memory");
        else             asm volatile("s_waitcnt vmcnt(0)" ::: "memory");
        asm volatile("s_barrier" ::: "memory");
        if (kt + 2 < KT) stage((kt + 2) % 3, (kt + 2) * 32);
        short8 a[2], b[4];
#pragma unroll
        for (int i = 0; i < 2; ++i)
            a[i] = *(const short8*)&As[cur][(wm + i * 16 + fr) * 32 + psl];
#pragma unroll
        for (int j = 0; j < 4; ++j)
            b[j] = *(const short8*)&Bsh[cur][(wn + j * 16 + fr) * 32 + psl];
#pragma unroll
        for (int i = 0; i < 2; ++i)
#pragma unroll
            for (int j = 0; j < 4; ++j)
                acc[i][j] = __builtin_amdgcn_mfma_f32_16x16x32_bf16(a[i], b[j], acc[i][j], 0, 0, 0);
        cur = (cur + 1) % 3;
    }
    const int cr = (lane >> 4) * 4, cc = lane & 15;
#pragma unroll
    for (int i = 0; i < 2; ++i)
#pragma unroll
        for (int j = 0; j < 4; ++j)
#pragma unroll
            for (int r = 0; r < 4; ++r)
                C[(size_t)(m0 + wm + i * 16 + cr + r) * ldc + (n0 + wn + j * 16 + cc)] = acc[i][j][r];
}

// ---------- GEMM2 MFMA K-split: part[kb][4096][48] = xsb(chunk) @ Wxt^T ----------
__global__ __launch_bounds__(256) void kgemm2m(const uint16_t* __restrict__ xsb,
        const float* __restrict__ Wxt, float* __restrict__ part) {
    __shared__ uint16_t As[128 * 32];   // 8 KB bf16
    __shared__ float Bs[64 * 32];       // 8 KB f32
    const int t = threadIdx.x;
    const int w = t >> 6, lane = t & 63;
    const int kb = blockIdx.x;              // 0..15
    const int m0 = blockIdx.y * 128;
    const int kc = kb * 128;
    f32x4 acc[2][3] = {};

    const int srowA = t >> 2;                             // 0..63
    const int scolA = ((t & 3) ^ ((t >> 3) & 3)) * 8;     // elems
    const uint16_t* ga0 = xsb + (size_t)(m0 + srowA) * 2048 + scolA;
    const uint16_t* ga1 = xsb + (size_t)(m0 + 64 + srowA) * 2048 + scolA;
    uint16_t* lA0 = &As[w * 512];
    uint16_t* lA1 = &As[2048 + w * 512];

    const int srowB = t >> 3;                            // 0..31
    const int scolB = ((t & 7) ^ ((t >> 3) & 7)) * 4;    // floats
    float* lB[2];
#pragma unroll
    for (int r = 0; r < 2; ++r) lB[r] = &Bs[(r * 32 + w * 8) * 32];

    const int wm = w * 32;
    const int fr = lane & 15, fg = (lane >> 4) * 8;
    const int psl = (((fg >> 3) ^ ((fr >> 1) & 3)) << 3);   // bf16 A read slot
    const int plo = (((fg >> 2) ^ (fr & 7))) * 4;           // f32 B read slots
    const int phi = ((((fg >> 2) + 1) ^ (fr & 7))) * 4;

    for (int kt = 0; kt < 4; ++kt) {
        const int ko = kc + kt * 32;
        gload16(ga0 + ko, lA0);
        gload16(ga1 + ko, lA1);
#pragma unroll
        for (int r = 0; r < 2; ++r)
            gload16f(Wxt + (size_t)(r * 32 + srowB) * 2048 + ko + scolB, lB[r]);
        __syncthreads();
        short8 a[2], b[3];
#pragma unroll
        for (int i = 0; i < 2; ++i)
            a[i] = *(const short8*)&As[(wm + i * 16 + fr) * 32 + psl];
#pragma unroll
        for (int j = 0; j < 3; ++j) {
            const float* base = &Bs[(j * 16 + fr) * 32];
            b[j] = pack8(*(const float4*)&base[plo], *(const float4*)&base[phi]);
        }
#pragma unroll
        for (int i = 0; i < 2; ++i)
#pragma unroll
            for (int j = 0; j < 3; ++j)
                acc[i][j] = __builtin_amdgcn_mfma_f32_16x16x32_bf16(a[i], b[j], acc[i][j], 0, 0, 0);
        __syncthreads();
    }
    const int cr = (lane >> 4) * 4, cc = lane & 15;
    float* pb = part + (size_t)kb * 4096 * 48;
#pragma unroll
    for (int i = 0; i < 2; ++i)
#pragma unroll
        for (int j = 0; j < 3; ++j)
#pragma unroll
            for (int r = 0; r < 4; ++r)
                pb[(size_t)(m0 + wm + i * 16 + cr + r) * 48 + j * 16 + cc] = acc[i][j][r];
}

// ---------- fused: reduce partials -> bcd row; pack dtdx (over xzb row) + szw ----------
__global__ __launch_bounds__(256) void kredprep(const float* __restrict__ part,
        const float* __restrict__ wdt, const float* __restrict__ bdt,
        const float* __restrict__ Dp, const uint16_t* __restrict__ xsb,
        uint16_t* __restrict__ xzb_io, uint32_t* __restrict__ szw,
        float* __restrict__ bcd) {
    const int row = blockIdx.x;
    const int t = threadIdx.x;
    __shared__ float rawsh;
    if (t < 33) {
        float s = 0.f;
#pragma unroll
        for (int ks = 0; ks < KS2; ++ks)
            s += part[(size_t)ks * 4096 * 48 + (size_t)row * 48 + t];
        bcd[(size_t)row * BCD_LD + t] = s;
        if (t == 32) rawsh = s;
    }
    __syncthreads();
    const float raw = rawsh;
    ushort4 xu[2], zu[2];
#pragma unroll
    for (int g = 0; g < 2; ++g) {
        const int dg = t * 8 + g * 4;
        xu[g] = *(const ushort4*)&xsb[(size_t)row * 2048 + dg];
        zu[g] = *(const ushort4*)&xzb_io[(size_t)row * 4096 + 2048 + dg];
    }
    __syncthreads();          // all z reads done block-wide before row overwrite
    uint32_t* dtdx = (uint32_t*)xzb_io;
#pragma unroll
    for (int g = 0; g < 2; ++g) {
        const int dg = t * 8 + g * 4;
        const float4 w  = *(const float4*)&wdt[dg];
        const float4 b  = *(const float4*)&bdt[dg];
        const float4 Dv = *(const float4*)&Dp[dg];
        const float x0 = bf2f(xu[g].x), x1 = bf2f(xu[g].y);
        const float x2 = bf2f(xu[g].z), x3 = bf2f(xu[g].w);
        const float dt0 = softplus_f(raw * w.x + b.x);
        const float dt1 = softplus_f(raw * w.y + b.y);
        const float dt2 = softplus_f(raw * w.z + b.z);
        const float dt3 = softplus_f(raw * w.w + b.w);
        uint4 pd;
        pd.x = pack2bf(dt0, dt0 * x0);
        pd.y = pack2bf(dt1, dt1 * x1);
        pd.z = pack2bf(dt2, dt2 * x2);
        pd.w = pack2bf(dt3, dt3 * x3);
        const float s0 = silu_f(bf2f(zu[g].x)), s1 = silu_f(bf2f(zu[g].y));
        const float s2 = silu_f(bf2f(zu[g].z)), s3 = silu_f(bf2f(zu[g].w));
        uint4 ps;
        ps.x = pack2bf(s0, x0 * Dv.x * s0);
        ps.y = pack2bf(s1, x1 * Dv.y * s1);
        ps.z = pack2bf(s2, x2 * Dv.z * s2);
        ps.w = pack2bf(s3, x3 * Dv.w * s3);
        *(uint4*)&dtdx[(size_t)row * 2048 + dg] = pd;
        *(uint4*)&szw[(size_t)row * 2048 + dg] = ps;
    }
}

// ---------- scan phase 1: 1 ch/thread (2 lanes/ch, 8 states each), full occupancy ----------
__global__ __launch_bounds__(256) void kscan1(const uint32_t* __restrict__ dtdx,
        const float* __restrict__ bcd, const float* __restrict__ Alog,
        float* __restrict__ hbuf, float* __restrict__ sumdt) {
    const int T = blockIdx.x * 256 + threadIdx.x;
    const int sub = T & 1;
    const int ch  = (T >> 1) & 4095;
    const int chunk = T >> 13;
    const int b = ch >> 11, d = ch & 2047;
    const int row0 = b * SEQLEN + chunk * CHUNKLEN;    // uniform per block

    __shared__ float Bls[32][16];       // B part (cols 0..15) of the 32 chunk rows
    {
        const int r = threadIdx.x >> 3, c = (threadIdx.x & 7) * 2;
        const float2 v = *(const float2*)&bcd[(size_t)(row0 + r) * BCD_LD + c];
        Bls[r][c] = v.x; Bls[r][c + 1] = v.y;
    }
    __syncthreads();

    float Ae[8]; bool st = true;
#pragma unroll
    for (int i = 0; i < 8; ++i) {
        const float a0 = __expf(Alog[d * 16 + sub * 8 + i]);
        Ae[i] = -a0 * L2E;
        st = st && (fabsf(a0 - (float)(sub * 8 + i + 1)) < 1e-3f);
    }
    float h[8] = {};
    float sdt = 0.f;
    const uint32_t* pD = dtdx + (size_t)row0 * 2048 + d;
    if (st) {
        for (int l0 = 0; l0 < CHUNKLEN; l0 += 4) {
            uint32_t pk[4];
#pragma unroll
            for (int s = 0; s < 4; ++s) pk[s] = pD[(size_t)s * 2048];
#pragma unroll
            for (int s = 0; s < 4; ++s) {
                const float4 B0 = *(const float4*)&Bls[l0 + s][sub * 8];
                const float4 B1 = *(const float4*)&Bls[l0 + s][sub * 8 + 4];
                const float dt  = __uint_as_float(pk[s] << 16);
                const float dtx = __uint_as_float(pk[s] & 0xffff0000u);
                sdt += dt;
                const float e0 = __builtin_amdgcn_exp2f(dt * (-L2E));
                const float e2 = e0 * e0, e4 = e2 * e2;
                const float bs = sub ? (e4 * e4) : 1.f;
                const float d0 = bs * e0, d1 = bs * e2;
                const float d2 = d1 * e0, d3 = d1 * e2;
                const float d4 = d3 * e0, d5 = d3 * e2;
                const float d6 = d5 * e0, d7 = d5 * e2;
                h[0] = fmaf(d0, h[0], dtx * B0.x);
                h[1] = fmaf(d1, h[1], dtx * B0.y);
                h[2] = fmaf(d2, h[2], dtx * B0.z);
                h[3] = fmaf(d3, h[3], dtx * B0.w);
                h[4] = fmaf(d4, h[4], dtx * B1.x);
                h[5] = fmaf(d5, h[5], dtx * B1.y);
                h[6] = fmaf(d6, h[6], dtx * B1.z);
                h[7] = fmaf(d7, h[7], dtx * B1.w);
            }
            pD += 4 * 2048;
        }
    } else {
        for (int l0 = 0; l0 < CHUNKLEN; l0 += 4) {
            uint32_t pk[4];
#pragma unroll
            for (int s = 0; s < 4; ++s) pk[s] = pD[(size_t)s * 2048];
#pragma unroll
            for (int s = 0; s < 4; ++s) {
                const float4 B0 = *(const float4*)&Bls[l0 + s][sub * 8];
                const float4 B1 = *(const float4*)&Bls[l0 + s][sub * 8 + 4];
                const float dt  = __uint_as_float(pk[s] << 16);
                const float dtx = __uint_as_float(pk[s] & 0xffff0000u);
                sdt += dt;
                const float Bv[8] = {B0.x, B0.y, B0.z, B0.w, B1.x, B1.y, B1.z, B1.w};
#pragma unroll
                for (int i = 0; i < 8; ++i)
                    h[i] = fmaf(__builtin_amdgcn_exp2f(dt * Ae[i]), h[i], dtx * Bv[i]);
            }
            pD += 4 * 2048;
        }
    }
    const size_t cc0 = (size_t)(chunk * 4096 + ch) * 16 + sub * 8;
    *(float4*)&hbuf[cc0]     = make_float4(h[0], h[1], h[2], h[3]);
    *(float4*)&hbuf[cc0 + 4] = make_float4(h[4], h[5], h[6], h[7]);
    if (sub == 0) sumdt[chunk * 4096 + ch] = sdt;
}

// ---------- scan phase 2: chunk combine (in-place carries), next-iter prefetch ----------
__global__ void kscan2(float* __restrict__ hbuf, const float* __restrict__ sumdt,
                       const float* __restrict__ Alog) {
    const int T = blockIdx.x * 256 + threadIdx.x;   // 65536
    const int n = T & 15, ch = T >> 4;
    const int d = ch & 2047;
    const float Ae = -__expf(Alog[d * 16 + n]) * L2E;
    float h = 0.f;
    size_t idx = (size_t)ch * 16 + n;
    float loc = hbuf[idx];
    float sd  = sumdt[ch];
    for (int c = 0; c < NCHUNK; ++c) {
        float locN = 0.f, sdN = 0.f;
        const size_t idxN = idx + (size_t)4096 * 16;
        if (c + 1 < NCHUNK) {
            locN = hbuf[idxN];
            sdN  = sumdt[(size_t)(c + 1) * 4096 + ch];
        }
        hbuf[idx] = h;
        h = __builtin_amdgcn_exp2f(Ae * sd) * h + loc;
        loc = locN; sd = sdN; idx = idxN;
    }
}

// ---------- scan phase 3: 1 ch/thread, bcd B+C in LDS, full occupancy ----------
__global__ __launch_bounds__(256) void kscan3(const uint32_t* __restrict__ dtdx,
        const float* __restrict__ bcd, const float* __restrict__ Alog,
        const uint32_t* __restrict__ szw, const float* __restrict__ hbuf,
        uint16_t* __restrict__ u) {
    const int T = blockIdx.x * 256 + threadIdx.x;
    const int sub = T & 1;
    const int ch  = (T >> 1) & 4095;
    const int chunk = T >> 13;
    const int b = ch >> 11, d = ch & 2047;
    const int row0 = b * SEQLEN + chunk * CHUNKLEN;    // uniform per block

    __shared__ float BC[32][32];        // B (0..15) + C (16..31) of the 32 chunk rows
    {
        const int r = threadIdx.x >> 3, c = (threadIdx.x & 7) * 4;
        *(float4*)&BC[r][c] = *(const float4*)&bcd[(size_t)(row0 + r) * BCD_LD + c];
    }
    __syncthreads();

    float Ae[8]; bool st = true;
#pragma unroll
    for (int i = 0; i < 8; ++i) {
        const float a0 = __expf(Alog[d * 16 + sub * 8 + i]);
        Ae[i] = -a0 * L2E;
        st = st && (fabsf(a0 - (float)(sub * 8 + i + 1)) < 1e-3f);
    }
    float h[8];
    {
        const size_t cc0 = (size_t)(chunk * 4096 + ch) * 16 + sub * 8;
        const float4 a0 = *(const float4*)&hbuf[cc0];
        const float4 a1 = *(const float4*)&hbuf[cc0 + 4];
        h[0]=a0.x; h[1]=a0.y; h[2]=a0.z; h[3]=a0.w;
        h[4]=a1.x; h[5]=a1.y; h[6]=a1.z; h[7]=a1.w;
    }
    const uint32_t* pD = dtdx + (size_t)row0 * 2048 + d;
    const uint32_t* pS = szw  + (size_t)row0 * 2048 + d;   // only sub==0 reads
    uint16_t* pU = u + (size_t)row0 * D_INNER + d;
    if (st) {
        for (int l0 = 0; l0 < CHUNKLEN; l0 += 4) {
            uint32_t pk[4], qk[4];
#pragma unroll
            for (int s = 0; s < 4; ++s) {
                pk[s] = pD[(size_t)s * 2048];
                if (sub == 0) qk[s] = pS[(size_t)s * 2048];
            }
#pragma unroll
            for (int s = 0; s < 4; ++s) {
                const float4 B0 = *(const float4*)&BC[l0 + s][sub * 8];
                const float4 B1 = *(const float4*)&BC[l0 + s][sub * 8 + 4];
                const float4 C0 = *(const float4*)&BC[l0 + s][16 + sub * 8];
                const float4 C1 = *(const float4*)&BC[l0 + s][20 + sub * 8];
                const float dt  = __uint_as_float(pk[s] << 16);
                const float dtx = __uint_as_float(pk[s] & 0xffff0000u);
                const float e0 = __builtin_amdgcn_exp2f(dt * (-L2E));
                const float e2 = e0 * e0, e4 = e2 * e2;
                const float bs = sub ? (e4 * e4) : 1.f;
                const float d0 = bs * e0, d1 = bs * e2;
                const float d2 = d1 * e0, d3 = d1 * e2;
                const float d4 = d3 * e0, d5 = d3 * e2;
                const float d6 = d5 * e0, d7 = d5 * e2;
                h[0] = fmaf(d0, h[0], dtx * B0.x);
                h[1] = fmaf(d1, h[1], dtx * B0.y);
                h[2] = fmaf(d2, h[2], dtx * B0.z);
                h[3] = fmaf(d3, h[3], dtx * B0.w);
                h[4] = fmaf(d4, h[4], dtx * B1.x);
                h[5] = fmaf(d5, h[5], dtx * B1.y);
                h[6] = fmaf(d6, h[6], dtx * B1.z);
                h[7] = fmaf(d7, h[7], dtx * B1.w);
                float y = ((h[0]*C0.x + h[1]*C0.y) + (h[2]*C0.z + h[3]*C0.w))
                        + ((h[4]*C1.x + h[5]*C1.y) + (h[6]*C1.z + h[7]*C1.w));
                y += __shfl_xor(y, 1);
                if (sub == 0) {
                    const float sz = __uint_as_float(qk[s] << 16);
                    const float w2 = __uint_as_float(qk[s] & 0xffff0000u);
                    pU[(size_t)s * D_INNER] = f2bf(fmaf(y, sz, w2));
                }
            }
            pD += 4 * 2048; pS += 4 * 2048; pU += 4 * D_INNER;
        }
    } else {
        for (int l0 = 0; l0 < CHUNKLEN; l0 += 4) {
            uint32_t pk[4], qk[4];
#pragma unroll
            for (int s = 0; s < 4; ++s) {
                pk[s] = pD[(size_t)s * 2048];
                if (sub == 0) qk[s] = pS[(size_t)s * 2048];
            }
#pragma unroll
            for (int s = 0; s < 4; ++s) {
                const float4 B0 = *(const float4*)&BC[l0 + s][sub * 8];
                const float4 B1 = *(const float4*)&BC[l0 + s][sub * 8 + 4];
                const float4 C0 = *(const float4*)&BC[l0 + s][16 + sub * 8];
                const float4 C1 = *(const float4*)&BC[l0 + s][20 + sub * 8];
                const float dt  = __uint_as_float(pk[s] << 16);
                const float dtx = __uint_as_float(pk[s] & 0xffff0000u);
                const float Bv[8] = {B0.x, B0.y, B0.z, B0.w, B1.x, B1.y, B1.z, B1.w};
                const float Cv[8] = {C0.x, C0.y, C0.z, C0.w, C1.x, C1.y, C1.z, C1.w};
                float y = 0.f;
#pragma unroll
                for (int i = 0; i < 8; ++i) {
                    h[i] = fmaf(__builtin_amdgcn_exp2f(dt * Ae[i]), h[i], dtx * Bv[i]);
                    y = fmaf(h[i], Cv[i], y);
                }
                y += __shfl_xor(y, 1);
                if (sub == 0) {
                    const float sz = __uint_as_float(qk[s] << 16);
                    const float w2 = __uint_as_float(qk[s] & 0xffff0000u);
                    pU[(size_t)s * D_INNER] = f2bf(fmaf(y, sz, w2));
                }
            }
            pD += 4 * 2048; pS += 4 * 2048; pU += 4 * D_INNER;
        }
    }
}

// ---------- causal depthwise conv (k=4) + bias + SiLU, 2 ch/thread, bf16 out ----------
__global__ void kconv(const uint16_t* __restrict__ xzb, const float* __restrict__ cw,
                      const float* __restrict__ cb, uint16_t* __restrict__ xsb) {
    const int T = blockIdx.x * 256 + threadIdx.x;   // over NROWS*1024
    const int d0 = (T & 1023) * 2;
    const int row = T >> 10;
    const int l = row & (SEQLEN - 1), b = row >> 11;
    const float4 wA = *(const float4*)&cw[d0 * 4];
    const float4 wB = *(const float4*)&cw[d0 * 4 + 4];
    const float2 bias = *(const float2*)&cb[d0];
    float a0 = bias.x, a1 = bias.y;
    const size_t base = (size_t)b * SEQLEN;
    if (l >= 3) {
        uint32_t v;
        v = *(const uint32_t*)&xzb[(base + l - 3) * 4096 + d0];
        a0 += wA.x * bf2f((uint16_t)v); a1 += wB.x * bf2f((uint16_t)(v >> 16));
        v = *(const uint32_t*)&xzb[(base + l - 2) * 4096 + d0];
        a0 += wA.y * bf2f((uint16_t)v); a1 += wB.y * bf2f((uint16_t)(v >> 16));
        v = *(const uint32_t*)&xzb[(base + l - 1) * 4096 + d0];
        a0 += wA.z * bf2f((uint16_t)v); a1 += wB.z * bf2f((uint16_t)(v >> 16));
        v = *(const uint32_t*)&xzb[(base + l    ) * 4096 + d0];
        a0 += wA.w * bf2f((uint16_t)v); a1 += wB.w * bf2f((uint16_t)(v >> 16));
    } else {
        uint32_t v;
        if (l >= 2) {
            v = *(const uint32_t*)&xzb[(base + l - 2) * 4096 + d0];
            a0 += wA.y * bf2f((uint16_t)v); a1 += wB.y * bf2f((uint16_t)(v >> 16));
        }
        if (l >= 1) {
            v = *(const uint32_t*)&xzb[(base + l - 1) * 4096 + d0];
            a0 += wA.z * bf2f((uint16_t)v); a1 += wB.z * bf2f((uint16_t)(v >> 16));
        }
        v = *(const uint32_t*)&xzb[(base + l) * 4096 + d0];
        a0 += wA.w * bf2f((uint16_t)v); a1 += wB.w * bf2f((uint16_t)(v >> 16));
    }
    *(uint32_t*)&xsb[(size_t)row * 2048 + d0] = pack2bf(silu_f(a0), silu_f(a1));
}

extern "C" void kernel_launch(void* const* d_in, const int* in_sizes, int n_in,
                              void* d_out, int out_size, void* d_ws, size_t ws_size,
                              hipStream_t stream) {
    const float* x      = (const float*)d_in[0];
    const float* W_in   = (const float*)d_in[1];
    const float* conv_w = (const float*)d_in[2];
    const float* conv_b = (const float*)d_in[3];
    const float* W_x    = (const float*)d_in[4];
    const float* w_dt   = (const float*)d_in[5];
    const float* b_dt   = (const float*)d_in[6];
    const float* A_log  = (const float*)d_in[7];
    const float* Dp     = (const float*)d_in[8];
    const float* W_out  = (const float*)d_in[9];
    float* out = (float*)d_out;

    char* p = (char*)d_ws;
    uint16_t* xb  = (uint16_t*)p;  p += (size_t)NROWS * D_MODEL * 2;      // 8 MB (dead after gemm1)
    uint16_t* Wb  = (uint16_t*)p;  p += (size_t)4096 * 1024 * 2;          // 8 MB (dead after gemm1)
    uint16_t* Wob = (uint16_t*)p;  p += (size_t)1024 * 2048 * 2;          // 4 MB  (W_out^T)
    uint16_t* xzb = (uint16_t*)p;  p += (size_t)NROWS * 4096 * 2;         // 32 MB (bf16 xz; later dtdx)
    uint16_t* xsb = (uint16_t*)p;  p += (size_t)NROWS * D_INNER * 2;      // 16 MB (bf16 xs)
    float* bcd    = (float*)p;     p += (size_t)NROWS * BCD_LD * 4;       // 576 KB
    float* sumdt  = (float*)p;     p += (size_t)NCHUNK * 4096 * 4;        // 1 MB
    float* Wxt    = (float*)p;     p += (size_t)64 * 2048 * 4;            // 512 KB
    uint16_t* ub  = (uint16_t*)p;  p += (size_t)NROWS * D_INNER * 2;      // 16 MB
    uint32_t* szw = (uint32_t*)p;  p += (size_t)NROWS * D_INNER * 4;      // 32 MB (silu(z) pack)
    // overlays (regions dead during their use):
    float* hbuf    = (float*)xb;        // 16 MB = xb+Wb (dead after gemm1)
    float* part    = (float*)ub;        // 12.6 MB (ub written only by kscan3, later)
    uint32_t* dtdx = (uint32_t*)xzb;    // packed (dt, dt*x), in-place over xzb rows

    // 1) fused input prep (cvt + 2 transposes + Wxt)
    kprep0<<<10752, 256, 0, stream>>>(x, xb, W_in, Wb, W_out, Wob, W_x, Wxt);
    // 2) xz = x @ W_in   (M=4096, N=4096, K=1024), 256x256 blocks, 4-buf vmcnt(8)
    kgemm256d<1024, 4><<<dim3(16, 16), 512, 0, stream>>>(xb, Wb, xzb, 4096);
    // 3) conv + silu (bf16 in, bf16 out), 2 ch/thread
    kconv<<<NROWS * 1024 / 256, 256, 0, stream>>>(xzb, conv_w, conv_b, xsb);
    // 4) bcd partials = xsb @ W_x  (MFMA, K-split 16, bf16 A)
    kgemm2m<<<dim3(KS2, 32), 256, 0, stream>>>(xsb, Wxt, part);
    // 5) fused reduce + scan-operand packing (dtdx over xzb rows, szw separate)
    kredprep<<<NROWS, 256, 0, stream>>>(part, w_dt, b_dt, Dp, xsb, xzb, szw, bcd);
    // 6) selective scan (3 phases), 1 ch/thread (2048 blocks), tree-decay ILP
    kscan1<<<(4096 * 2 * NCHUNK) / 256, 256, 0, stream>>>(dtdx, bcd, A_log, hbuf, sumdt);
    kscan2<<<(4096 * 16) / 256, 256, 0, stream>>>(hbuf, sumdt, A_log);
    kscan3<<<(4096 * 2 * NCHUNK) / 256, 256, 0, stream>>>(dtdx, bcd, A_log, szw, hbuf, ub);
    // 7) out = u @ W_out (M=4096, N=1024, K=2048), 3-buf counted-vmcnt
    kgemm64<2048, 3><<<dim3(1024 / 128, 4096 / 64), 256, 0, stream>>>(ub, Wob, out, 1024);
}

// Round 18
// 200.408 us; speedup vs baseline: 1.0262x; 1.0262x over previous
//
#include <hip/hip_runtime.h>
#include <hip/hip_bf16.h>
#include <stdint.h>

#define D_MODEL 1024
#define D_STATE 16
#define D_CONV  4
#define D_INNER 2048
#define BATCH   2
#define SEQLEN  2048
#define NROWS   (BATCH*SEQLEN)     // 4096
#define BCD_LD  36                 // padded leading dim for bcd (33 used)
#define NCHUNK  64
#define CHUNKLEN (SEQLEN/NCHUNK)   // 32
#define KS2     16                 // K-splits for GEMM2 (chunk = 128)
#define L2E 1.44269504088896340f

typedef __attribute__((ext_vector_type(8))) short   short8;
typedef __attribute__((ext_vector_type(4))) float   f32x4;

__device__ __forceinline__ uint16_t f2bf(float f) {        // RNE f32->bf16
    uint32_t u = __float_as_uint(f);
    return (uint16_t)((u + 0x7FFFu + ((u >> 16) & 1u)) >> 16);
}
__device__ __forceinline__ float bf2f(uint16_t h) {
    return __uint_as_float(((uint32_t)h) << 16);
}
__device__ __forceinline__ uint32_t pack2bf(float lo, float hi) {
    return (uint32_t)f2bf(lo) | ((uint32_t)f2bf(hi) << 16);
}
__device__ __forceinline__ void gload16(const uint16_t* g, uint16_t* l) {
    __builtin_amdgcn_global_load_lds(
        (const __attribute__((address_space(1))) void*)g,
        (__attribute__((address_space(3))) void*)l, 16, 0, 0);
}
__device__ __forceinline__ void gload16f(const float* g, float* l) {
    __builtin_amdgcn_global_load_lds(
        (const __attribute__((address_space(1))) void*)g,
        (__attribute__((address_space(3))) void*)l, 16, 0, 0);
}
__device__ __forceinline__ float softplus_f(float v) {
    return fmaxf(v, 0.f) + __logf(1.f + __expf(-fabsf(v)));
}
__device__ __forceinline__ float silu_f(float v) {
    return v / (1.f + __expf(-v));
}
__device__ __forceinline__ short8 pack8(const float4 lo, const float4 hi) {
    short8 r;
    r[0] = (short)f2bf(lo.x); r[1] = (short)f2bf(lo.y);
    r[2] = (short)f2bf(lo.z); r[3] = (short)f2bf(lo.w);
    r[4] = (short)f2bf(hi.x); r[5] = (short)f2bf(hi.y);
    r[6] = (short)f2bf(hi.z); r[7] = (short)f2bf(hi.w);
    return r;
}

// ---------- fused input prep: kcvt | ktrans(W_in) | ktrans(W_out) | kwxt ----------
__global__ void kprep0(const float* __restrict__ x, uint16_t* __restrict__ xb,
                       const float* __restrict__ W_in, uint16_t* __restrict__ Wb,
                       const float* __restrict__ W_out, uint16_t* __restrict__ Wob,
                       const float* __restrict__ Wx, float* __restrict__ Wxt) {
    __shared__ float tile[32][33];
    const int blk = blockIdx.x;
    const int tid = threadIdx.x;
    if (blk < 4096) {                          // ---- cvt x -> bf16 (1M float4s)
        const int T = blk * 256 + tid;
        const float4 v = *(const float4*)&x[(size_t)T * 4];
        ushort4 o;
        o.x = f2bf(v.x); o.y = f2bf(v.y); o.z = f2bf(v.z); o.w = f2bf(v.w);
        *(ushort4*)&xb[(size_t)T * 4] = o;
    } else if (blk < 8192) {                   // ---- W_in [1024][4096] -> Wb [4096][1024]
        const int bb = blk - 4096;
        const int n0 = (bb & 127) * 32, k0 = (bb >> 7) * 32;
        const int tx = tid & 31, ty = tid >> 5;
#pragma unroll
        for (int i = 0; i < 4; ++i)
            tile[ty + i * 8][tx] = W_in[(size_t)(k0 + ty + i * 8) * 4096 + n0 + tx];
        __syncthreads();
#pragma unroll
        for (int i = 0; i < 4; ++i)
            Wb[(size_t)(n0 + ty + i * 8) * 1024 + k0 + tx] = f2bf(tile[tx][ty + i * 8]);
    } else if (blk < 10240) {                  // ---- W_out [2048][1024] -> Wob [1024][2048]
        const int bb = blk - 8192;
        const int n0 = (bb & 31) * 32, k0 = (bb >> 5) * 32;
        const int tx = tid & 31, ty = tid >> 5;
#pragma unroll
        for (int i = 0; i < 4; ++i)
            tile[ty + i * 8][tx] = W_out[(size_t)(k0 + ty + i * 8) * 1024 + n0 + tx];
        __syncthreads();
#pragma unroll
        for (int i = 0; i < 4; ++i)
            Wob[(size_t)(n0 + ty + i * 8) * 2048 + k0 + tx] = f2bf(tile[tx][ty + i * 8]);
    } else {                                   // ---- Wxt[64][2048] = W_x^T zero-padded
        const int T = (blk - 10240) * 256 + tid;
        const int j = T >> 11, k = T & 2047;
        Wxt[T] = (j < 33) ? Wx[(size_t)k * 33 + j] : 0.f;
    }
}

// ---------- GEMM1: 256x128 tile, 512 thr, 3-buf counted-vmcnt pipeline ----------
template<int KDIM, int GXL>
__global__ __launch_bounds__(512) void kgemm256(const uint16_t* __restrict__ A,
                                                const uint16_t* __restrict__ B,
                                                uint16_t* __restrict__ C, const int ldc) {
    __shared__ uint16_t As[3][256 * 32];   // 3 x 16 KB
    __shared__ uint16_t Bsh[3][128 * 32];  // 3 x 8 KB  (72 KB total)
    const int t = threadIdx.x;          // 0..511
    const int w = t >> 6, lane = t & 63;
    int wg = blockIdx.y * (1 << GXL) + blockIdx.x;
    wg = (wg & 7) * ((gridDim.x * gridDim.y) >> 3) + (wg >> 3);   // bijective XCD swizzle
    const int m0 = (wg >> GXL) * 256, n0 = (wg & ((1 << GXL) - 1)) * 128;
    const int wm = (w >> 1) * 64, wn = (w & 1) * 64;
    f32x4 acc[4][4] = {};

    const int srow = t >> 2;                              // 0..127
    const int scol = ((t & 3) ^ ((t >> 3) & 3)) * 8;      // pre-swizzled source slot
    const uint16_t* ga0 = A + (size_t)(m0 + srow) * KDIM + scol;
    const uint16_t* ga1 = A + (size_t)(m0 + 128 + srow) * KDIM + scol;
    const uint16_t* gb0 = B + (size_t)(n0 + srow) * KDIM + scol;

    const int fr = lane & 15, fg = (lane >> 4) * 8;
    const int psl = (((fg >> 3) ^ ((fr >> 1) & 3)) << 3);

    auto stage = [&](int buf, int ko) {
        gload16(ga0 + ko, &As[buf][w * 512]);
        gload16(ga1 + ko, &As[buf][4096 + w * 512]);
        gload16(gb0 + ko, &Bsh[buf][w * 512]);
    };

    constexpr int KT = KDIM / 32;
    stage(0, 0);
    stage(1, 32);                       // 6 loads in flight
    int cur = 0;
    for (int kt = 0; kt < KT; ++kt) {
        if (kt + 1 < KT) asm volatile("s_waitcnt vmcnt(3)" ::: "memory");
        else             asm volatile("s_waitcnt vmcnt(0)" ::: "memory");
        asm volatile("s_barrier" ::: "memory");      // all waves' tile-kt loads landed
        if (kt + 2 < KT) stage((kt + 2) % 3, (kt + 2) * 32);
        short8 a[4], b[4];
#pragma unroll
        for (int i = 0; i < 4; ++i) {
            a[i] = *(const short8*)&As[cur][(wm + i * 16 + fr) * 32 + psl];
            b[i] = *(const short8*)&Bsh[cur][(wn + i * 16 + fr) * 32 + psl];
        }
#pragma unroll
        for (int i = 0; i < 4; ++i)
#pragma unroll
            for (int j = 0; j < 4; ++j)
                acc[i][j] = __builtin_amdgcn_mfma_f32_16x16x32_bf16(a[i], b[j], acc[i][j], 0, 0, 0);
        cur = (cur + 1) % 3;
    }
    const int cr = (lane >> 4) * 4, cc = lane & 15;
#pragma unroll
    for (int i = 0; i < 4; ++i)
#pragma unroll
        for (int j = 0; j < 4; ++j)
#pragma unroll
            for (int r = 0; r < 4; ++r)
                C[(size_t)(m0 + wm + i * 16 + cr + r) * ldc + (n0 + wn + j * 16 + cc)] =
                    f2bf(acc[i][j][r]);
}

// ---------- GEMM3: 64x128 tile, 3-buf counted-vmcnt pipeline, f32 C ----------
template<int KDIM, int GXL>
__global__ __launch_bounds__(256) void kgemm64(const uint16_t* __restrict__ A,
                                               const uint16_t* __restrict__ B,
                                               float* __restrict__ C, const int ldc) {
    __shared__ uint16_t As[3][64 * 32];      // 3 x 4 KB
    __shared__ uint16_t Bsh[3][128 * 32];    // 3 x 8 KB  (36 KB total)
    const int t = threadIdx.x;
    const int w = t >> 6, lane = t & 63;
    int wg = blockIdx.y * (1 << GXL) + blockIdx.x;
    wg = (wg & 7) * ((gridDim.x * gridDim.y) >> 3) + (wg >> 3);
    const int m0 = (wg >> GXL) * 64, n0 = (wg & ((1 << GXL) - 1)) * 128;
    const int wm = (w >> 1) * 32, wn = (w & 1) * 64;
    f32x4 acc[2][4] = {};

    const int srow = t >> 2;
    const int scol = ((t & 3) ^ ((t >> 3) & 3)) * 8;
    const uint16_t* ga0 = A + (size_t)(m0 + srow) * KDIM + scol;
    const uint16_t* gb0 = B + (size_t)(n0 + srow) * KDIM + scol;
    const uint16_t* gb1 = B + (size_t)(n0 + 64 + srow) * KDIM + scol;

    const int fr = lane & 15, fg = (lane >> 4) * 8;
    const int psl = (((fg >> 3) ^ ((fr >> 1) & 3)) << 3);

    auto stage = [&](int buf, int ko) {
        gload16(ga0 + ko, &As[buf][w * 512]);
        gload16(gb0 + ko, &Bsh[buf][w * 512]);
        gload16(gb1 + ko, &Bsh[buf][2048 + w * 512]);
    };

    constexpr int KT = KDIM / 32;
    stage(0, 0);
    stage(1, 32);
    int cur = 0;
    for (int kt = 0; kt < KT; ++kt) {
        if (kt + 1 < KT) asm volatile("s_waitcnt vmcnt(3)" ::: "memory");
        else             asm volatile("s_waitcnt vmcnt(0)" ::: "memory");
        asm volatile("s_barrier" ::: "memory");
        if (kt + 2 < KT) stage((kt + 2) % 3, (kt + 2) * 32);
        short8 a[2], b[4];
#pragma unroll
        for (int i = 0; i < 2; ++i)
            a[i] = *(const short8*)&As[cur][(wm + i * 16 + fr) * 32 + psl];
#pragma unroll
        for (int j = 0; j < 4; ++j)
            b[j] = *(const short8*)&Bsh[cur][(wn + j * 16 + fr) * 32 + psl];
#pragma unroll
        for (int i = 0; i < 2; ++i)
#pragma unroll
            for (int j = 0; j < 4; ++j)
                acc[i][j] = __builtin_amdgcn_mfma_f32_16x16x32_bf16(a[i], b[j], acc[i][j], 0, 0, 0);
        cur = (cur + 1) % 3;
    }
    const int cr = (lane >> 4) * 4, cc = lane & 15;
#pragma unroll
    for (int i = 0; i < 2; ++i)
#pragma unroll
        for (int j = 0; j < 4; ++j)
#pragma unroll
            for (int r = 0; r < 4; ++r)
                C[(size_t)(m0 + wm + i * 16 + cr + r) * ldc + (n0 + wn + j * 16 + cc)] = acc[i][j][r];
}

// ---------- GEMM2 MFMA K-split: part[kb][4096][48] = xsb(chunk) @ Wxt^T ----------
__global__ __launch_bounds__(256) void kgemm2m(const uint16_t* __restrict__ xsb,
        const float* __restrict__ Wxt, float* __restrict__ part) {
    __shared__ uint16_t As[128 * 32];   // 8 KB bf16
    __shared__ float Bs[64 * 32];       // 8 KB f32
    const int t = threadIdx.x;
    const int w = t >> 6, lane = t & 63;
    const int kb = blockIdx.x;              // 0..15
    const int m0 = blockIdx.y * 128;
    const int kc = kb * 128;
    f32x4 acc[2][3] = {};

    const int srowA = t >> 2;                             // 0..63
    const int scolA = ((t & 3) ^ ((t >> 3) & 3)) * 8;     // elems
    const uint16_t* ga0 = xsb + (size_t)(m0 + srowA) * 2048 + scolA;
    const uint16_t* ga1 = xsb + (size_t)(m0 + 64 + srowA) * 2048 + scolA;
    uint16_t* lA0 = &As[w * 512];
    uint16_t* lA1 = &As[2048 + w * 512];

    const int srowB = t >> 3;                            // 0..31
    const int scolB = ((t & 7) ^ ((t >> 3) & 7)) * 4;    // floats
    float* lB[2];
#pragma unroll
    for (int r = 0; r < 2; ++r) lB[r] = &Bs[(r * 32 + w * 8) * 32];

    const int wm = w * 32;
    const int fr = lane & 15, fg = (lane >> 4) * 8;
    const int psl = (((fg >> 3) ^ ((fr >> 1) & 3)) << 3);   // bf16 A read slot
    const int plo = (((fg >> 2) ^ (fr & 7))) * 4;           // f32 B read slots
    const int phi = ((((fg >> 2) + 1) ^ (fr & 7))) * 4;

    for (int kt = 0; kt < 4; ++kt) {
        const int ko = kc + kt * 32;
        gload16(ga0 + ko, lA0);
        gload16(ga1 + ko, lA1);
#pragma unroll
        for (int r = 0; r < 2; ++r)
            gload16f(Wxt + (size_t)(r * 32 + srowB) * 2048 + ko + scolB, lB[r]);
        __syncthreads();
        short8 a[2], b[3];
#pragma unroll
        for (int i = 0; i < 2; ++i)
            a[i] = *(const short8*)&As[(wm + i * 16 + fr) * 32 + psl];
#pragma unroll
        for (int j = 0; j < 3; ++j) {
            const float* base = &Bs[(j * 16 + fr) * 32];
            b[j] = pack8(*(const float4*)&base[plo], *(const float4*)&base[phi]);
        }
#pragma unroll
        for (int i = 0; i < 2; ++i)
#pragma unroll
            for (int j = 0; j < 3; ++j)
                acc[i][j] = __builtin_amdgcn_mfma_f32_16x16x32_bf16(a[i], b[j], acc[i][j], 0, 0, 0);
        __syncthreads();
    }
    const int cr = (lane >> 4) * 4, cc = lane & 15;
    float* pb = part + (size_t)kb * 4096 * 48;
#pragma unroll
    for (int i = 0; i < 2; ++i)
#pragma unroll
        for (int j = 0; j < 3; ++j)
#pragma unroll
            for (int r = 0; r < 4; ++r)
                pb[(size_t)(m0 + wm + i * 16 + cr + r) * 48 + j * 16 + cc] = acc[i][j][r];
}

// ---------- fused: reduce partials -> bcd row; pack dtdx (over xzb row) + szw ----------
__global__ __launch_bounds__(256) void kredprep(const float* __restrict__ part,
        const float* __restrict__ wdt, const float* __restrict__ bdt,
        const float* __restrict__ Dp, const uint16_t* __restrict__ xsb,
        uint16_t* __restrict__ xzb_io, uint32_t* __restrict__ szw,
        float* __restrict__ bcd) {
    const int row = blockIdx.x;
    const int t = threadIdx.x;
    __shared__ float rawsh;
    if (t < 33) {
        float s = 0.f;
#pragma unroll
        for (int ks = 0; ks < KS2; ++ks)
            s += part[(size_t)ks * 4096 * 48 + (size_t)row * 48 + t];
        bcd[(size_t)row * BCD_LD + t] = s;
        if (t == 32) rawsh = s;
    }
    __syncthreads();
    const float raw = rawsh;
    ushort4 xu[2], zu[2];
#pragma unroll
    for (int g = 0; g < 2; ++g) {
        const int dg = t * 8 + g * 4;
        xu[g] = *(const ushort4*)&xsb[(size_t)row * 2048 + dg];
        zu[g] = *(const ushort4*)&xzb_io[(size_t)row * 4096 + 2048 + dg];
    }
    __syncthreads();          // all z reads done block-wide before row overwrite
    uint32_t* dtdx = (uint32_t*)xzb_io;
#pragma unroll
    for (int g = 0; g < 2; ++g) {
        const int dg = t * 8 + g * 4;
        const float4 w  = *(const float4*)&wdt[dg];
        const float4 b  = *(const float4*)&bdt[dg];
        const float4 Dv = *(const float4*)&Dp[dg];
        const float x0 = bf2f(xu[g].x), x1 = bf2f(xu[g].y);
        const float x2 = bf2f(xu[g].z), x3 = bf2f(xu[g].w);
        const float dt0 = softplus_f(raw * w.x + b.x);
        const float dt1 = softplus_f(raw * w.y + b.y);
        const float dt2 = softplus_f(raw * w.z + b.z);
        const float dt3 = softplus_f(raw * w.w + b.w);
        uint4 pd;
        pd.x = pack2bf(dt0, dt0 * x0);
        pd.y = pack2bf(dt1, dt1 * x1);
        pd.z = pack2bf(dt2, dt2 * x2);
        pd.w = pack2bf(dt3, dt3 * x3);
        const float s0 = silu_f(bf2f(zu[g].x)), s1 = silu_f(bf2f(zu[g].y));
        const float s2 = silu_f(bf2f(zu[g].z)), s3 = silu_f(bf2f(zu[g].w));
        uint4 ps;
        ps.x = pack2bf(s0, x0 * Dv.x * s0);
        ps.y = pack2bf(s1, x1 * Dv.y * s1);
        ps.z = pack2bf(s2, x2 * Dv.z * s2);
        ps.w = pack2bf(s3, x3 * Dv.w * s3);
        *(uint4*)&dtdx[(size_t)row * 2048 + dg] = pd;
        *(uint4*)&szw[(size_t)row * 2048 + dg] = ps;
    }
}

// ---------- scan phase 1: 1 ch/thread (2 lanes/ch, 8 states each), full occupancy ----------
__global__ __launch_bounds__(256) void kscan1(const uint32_t* __restrict__ dtdx,
        const float* __restrict__ bcd, const float* __restrict__ Alog,
        float* __restrict__ hbuf, float* __restrict__ sumdt) {
    const int T = blockIdx.x * 256 + threadIdx.x;
    const int sub = T & 1;
    const int ch  = (T >> 1) & 4095;
    const int chunk = T >> 13;
    const int b = ch >> 11, d = ch & 2047;
    const int row0 = b * SEQLEN + chunk * CHUNKLEN;    // uniform per block

    __shared__ float Bls[32][16];       // B part (cols 0..15) of the 32 chunk rows
    {
        const int r = threadIdx.x >> 3, c = (threadIdx.x & 7) * 2;
        const float2 v = *(const float2*)&bcd[(size_t)(row0 + r) * BCD_LD + c];
        Bls[r][c] = v.x; Bls[r][c + 1] = v.y;
    }
    __syncthreads();

    float Ae[8]; bool st = true;
#pragma unroll
    for (int i = 0; i < 8; ++i) {
        const float a0 = __expf(Alog[d * 16 + sub * 8 + i]);
        Ae[i] = -a0 * L2E;
        st = st && (fabsf(a0 - (float)(sub * 8 + i + 1)) < 1e-3f);
    }
    float h[8] = {};
    float sdt = 0.f;
    const uint32_t* pD = dtdx + (size_t)row0 * 2048 + d;
    if (st) {
        for (int l0 = 0; l0 < CHUNKLEN; l0 += 4) {
            uint32_t pk[4];
#pragma unroll
            for (int s = 0; s < 4; ++s) pk[s] = pD[(size_t)s * 2048];
#pragma unroll
            for (int s = 0; s < 4; ++s) {
                const float4 B0 = *(const float4*)&Bls[l0 + s][sub * 8];
                const float4 B1 = *(const float4*)&Bls[l0 + s][sub * 8 + 4];
                const float dt  = __uint_as_float(pk[s] << 16);
                const float dtx = __uint_as_float(pk[s] & 0xffff0000u);
                sdt += dt;
                const float e0 = __builtin_amdgcn_exp2f(dt * (-L2E));
                const float e2 = e0 * e0, e4 = e2 * e2;
                const float bs = sub ? (e4 * e4) : 1.f;
                const float d0 = bs * e0, d1 = bs * e2;
                const float d2 = d1 * e0, d3 = d1 * e2;
                const float d4 = d3 * e0, d5 = d3 * e2;
                const float d6 = d5 * e0, d7 = d5 * e2;
                h[0] = fmaf(d0, h[0], dtx * B0.x);
                h[1] = fmaf(d1, h[1], dtx * B0.y);
                h[2] = fmaf(d2, h[2], dtx * B0.z);
                h[3] = fmaf(d3, h[3], dtx * B0.w);
                h[4] = fmaf(d4, h[4], dtx * B1.x);
                h[5] = fmaf(d5, h[5], dtx * B1.y);
                h[6] = fmaf(d6, h[6], dtx * B1.z);
                h[7] = fmaf(d7, h[7], dtx * B1.w);
            }
            pD += 4 * 2048;
        }
    } else {
        for (int l0 = 0; l0 < CHUNKLEN; l0 += 4) {
            uint32_t pk[4];
#pragma unroll
            for (int s = 0; s < 4; ++s) pk[s] = pD[(size_t)s * 2048];
#pragma unroll
            for (int s = 0; s < 4; ++s) {
                const float4 B0 = *(const float4*)&Bls[l0 + s][sub * 8];
                const float4 B1 = *(const float4*)&Bls[l0 + s][sub * 8 + 4];
                const float dt  = __uint_as_float(pk[s] << 16);
                const float dtx = __uint_as_float(pk[s] & 0xffff0000u);
                sdt += dt;
                const float Bv[8] = {B0.x, B0.y, B0.z, B0.w, B1.x, B1.y, B1.z, B1.w};
#pragma unroll
                for (int i = 0; i < 8; ++i)
                    h[i] = fmaf(__builtin_amdgcn_exp2f(dt * Ae[i]), h[i], dtx * Bv[i]);
            }
            pD += 4 * 2048;
        }
    }
    const size_t cc0 = (size_t)(chunk * 4096 + ch) * 16 + sub * 8;
    *(float4*)&hbuf[cc0]     = make_float4(h[0], h[1], h[2], h[3]);
    *(float4*)&hbuf[cc0 + 4] = make_float4(h[4], h[5], h[6], h[7]);
    if (sub == 0) sumdt[chunk * 4096 + ch] = sdt;
}

// ---------- scan phase 2: chunk combine (in-place carries), next-iter prefetch ----------
__global__ void kscan2(float* __restrict__ hbuf, const float* __restrict__ sumdt,
                       const float* __restrict__ Alog) {
    const int T = blockIdx.x * 256 + threadIdx.x;   // 65536
    const int n = T & 15, ch = T >> 4;
    const int d = ch & 2047;
    const float Ae = -__expf(Alog[d * 16 + n]) * L2E;
    float h = 0.f;
    size_t idx = (size_t)ch * 16 + n;
    float loc = hbuf[idx];
    float sd  = sumdt[ch];
    for (int c = 0; c < NCHUNK; ++c) {
        float locN = 0.f, sdN = 0.f;
        const size_t idxN = idx + (size_t)4096 * 16;
        if (c + 1 < NCHUNK) {
            locN = hbuf[idxN];
            sdN  = sumdt[(size_t)(c + 1) * 4096 + ch];
        }
        hbuf[idx] = h;
        h = __builtin_amdgcn_exp2f(Ae * sd) * h + loc;
        loc = locN; sd = sdN; idx = idxN;
    }
}

// ---------- scan phase 3: 1 ch/thread, bcd B+C in LDS, full occupancy ----------
__global__ __launch_bounds__(256) void kscan3(const uint32_t* __restrict__ dtdx,
        const float* __restrict__ bcd, const float* __restrict__ Alog,
        const uint32_t* __restrict__ szw, const float* __restrict__ hbuf,
        uint16_t* __restrict__ u) {
    const int T = blockIdx.x * 256 + threadIdx.x;
    const int sub = T & 1;
    const int ch  = (T >> 1) & 4095;
    const int chunk = T >> 13;
    const int b = ch >> 11, d = ch & 2047;
    const int row0 = b * SEQLEN + chunk * CHUNKLEN;    // uniform per block

    __shared__ float BC[32][32];        // B (0..15) + C (16..31) of the 32 chunk rows
    {
        const int r = threadIdx.x >> 3, c = (threadIdx.x & 7) * 4;
        *(float4*)&BC[r][c] = *(const float4*)&bcd[(size_t)(row0 + r) * BCD_LD + c];
    }
    __syncthreads();

    float Ae[8]; bool st = true;
#pragma unroll
    for (int i = 0; i < 8; ++i) {
        const float a0 = __expf(Alog[d * 16 + sub * 8 + i]);
        Ae[i] = -a0 * L2E;
        st = st && (fabsf(a0 - (float)(sub * 8 + i + 1)) < 1e-3f);
    }
    float h[8];
    {
        const size_t cc0 = (size_t)(chunk * 4096 + ch) * 16 + sub * 8;
        const float4 a0 = *(const float4*)&hbuf[cc0];
        const float4 a1 = *(const float4*)&hbuf[cc0 + 4];
        h[0]=a0.x; h[1]=a0.y; h[2]=a0.z; h[3]=a0.w;
        h[4]=a1.x; h[5]=a1.y; h[6]=a1.z; h[7]=a1.w;
    }
    const uint32_t* pD = dtdx + (size_t)row0 * 2048 + d;
    const uint32_t* pS = szw  + (size_t)row0 * 2048 + d;   // only sub==0 reads
    uint16_t* pU = u + (size_t)row0 * D_INNER + d;
    if (st) {
        for (int l0 = 0; l0 < CHUNKLEN; l0 += 4) {
            uint32_t pk[4], qk[4];
#pragma unroll
            for (int s = 0; s < 4; ++s) {
                pk[s] = pD[(size_t)s * 2048];
                if (sub == 0) qk[s] = pS[(size_t)s * 2048];
            }
#pragma unroll
            for (int s = 0; s < 4; ++s) {
                const float4 B0 = *(const float4*)&BC[l0 + s][sub * 8];
                const float4 B1 = *(const float4*)&BC[l0 + s][sub * 8 + 4];
                const float4 C0 = *(const float4*)&BC[l0 + s][16 + sub * 8];
                const float4 C1 = *(const float4*)&BC[l0 + s][20 + sub * 8];
                const float dt  = __uint_as_float(pk[s] << 16);
                const float dtx = __uint_as_float(pk[s] & 0xffff0000u);
                const float e0 = __builtin_amdgcn_exp2f(dt * (-L2E));
                const float e2 = e0 * e0, e4 = e2 * e2;
                const float bs = sub ? (e4 * e4) : 1.f;
                const float d0 = bs * e0, d1 = bs * e2;
                const float d2 = d1 * e0, d3 = d1 * e2;
                const float d4 = d3 * e0, d5 = d3 * e2;
                const float d6 = d5 * e0, d7 = d5 * e2;
                h[0] = fmaf(d0, h[0], dtx * B0.x);
                h[1] = fmaf(d1, h[1], dtx * B0.y);
                h[2] = fmaf(d2, h[2], dtx * B0.z);
                h[3] = fmaf(d3, h[3], dtx * B0.w);
                h[4] = fmaf(d4, h[4], dtx * B1.x);
                h[5] = fmaf(d5, h[5], dtx * B1.y);
                h[6] = fmaf(d6, h[6], dtx * B1.z);
                h[7] = fmaf(d7, h[7], dtx * B1.w);
                float y = ((h[0]*C0.x + h[1]*C0.y) + (h[2]*C0.z + h[3]*C0.w))
                        + ((h[4]*C1.x + h[5]*C1.y) + (h[6]*C1.z + h[7]*C1.w));
                y += __shfl_xor(y, 1);
                if (sub == 0) {
                    const float sz = __uint_as_float(qk[s] << 16);
                    const float w2 = __uint_as_float(qk[s] & 0xffff0000u);
                    pU[(size_t)s * D_INNER] = f2bf(fmaf(y, sz, w2));
                }
            }
            pD += 4 * 2048; pS += 4 * 2048; pU += 4 * D_INNER;
        }
    } else {
        for (int l0 = 0; l0 < CHUNKLEN; l0 += 4) {
            uint32_t pk[4], qk[4];
#pragma unroll
            for (int s = 0; s < 4; ++s) {
                pk[s] = pD[(size_t)s * 2048];
                if (sub == 0) qk[s] = pS[(size_t)s * 2048];
            }
#pragma unroll
            for (int s = 0; s < 4; ++s) {
                const float4 B0 = *(const float4*)&BC[l0 + s][sub * 8];
                const float4 B1 = *(const float4*)&BC[l0 + s][sub * 8 + 4];
                const float4 C0 = *(const float4*)&BC[l0 + s][16 + sub * 8];
                const float4 C1 = *(const float4*)&BC[l0 + s][20 + sub * 8];
                const float dt  = __uint_as_float(pk[s] << 16);
                const float dtx = __uint_as_float(pk[s] & 0xffff0000u);
                const float Bv[8] = {B0.x, B0.y, B0.z, B0.w, B1.x, B1.y, B1.z, B1.w};
                const float Cv[8] = {C0.x, C0.y, C0.z, C0.w, C1.x, C1.y, C1.z, C1.w};
                float y = 0.f;
#pragma unroll
                for (int i = 0; i < 8; ++i) {
                    h[i] = fmaf(__builtin_amdgcn_exp2f(dt * Ae[i]), h[i], dtx * Bv[i]);
                    y = fmaf(h[i], Cv[i], y);
                }
                y += __shfl_xor(y, 1);
                if (sub == 0) {
                    const float sz = __uint_as_float(qk[s] << 16);
                    const float w2 = __uint_as_float(qk[s] & 0xffff0000u);
                    pU[(size_t)s * D_INNER] = f2bf(fmaf(y, sz, w2));
                }
            }
            pD += 4 * 2048; pS += 4 * 2048; pU += 4 * D_INNER;
        }
    }
}

// ---------- causal depthwise conv (k=4) + bias + SiLU, 2 ch/thread, bf16 out ----------
__global__ void kconv(const uint16_t* __restrict__ xzb, const float* __restrict__ cw,
                      const float* __restrict__ cb, uint16_t* __restrict__ xsb) {
    const int T = blockIdx.x * 256 + threadIdx.x;   // over NROWS*1024
    const int d0 = (T & 1023) * 2;
    const int row = T >> 10;
    const int l = row & (SEQLEN - 1), b = row >> 11;
    const float4 wA = *(const float4*)&cw[d0 * 4];
    const float4 wB = *(const float4*)&cw[d0 * 4 + 4];
    const float2 bias = *(const float2*)&cb[d0];
    float a0 = bias.x, a1 = bias.y;
    const size_t base = (size_t)b * SEQLEN;
    if (l >= 3) {
        uint32_t v;
        v = *(const uint32_t*)&xzb[(base + l - 3) * 4096 + d0];
        a0 += wA.x * bf2f((uint16_t)v); a1 += wB.x * bf2f((uint16_t)(v >> 16));
        v = *(const uint32_t*)&xzb[(base + l - 2) * 4096 + d0];
        a0 += wA.y * bf2f((uint16_t)v); a1 += wB.y * bf2f((uint16_t)(v >> 16));
        v = *(const uint32_t*)&xzb[(base + l - 1) * 4096 + d0];
        a0 += wA.z * bf2f((uint16_t)v); a1 += wB.z * bf2f((uint16_t)(v >> 16));
        v = *(const uint32_t*)&xzb[(base + l    ) * 4096 + d0];
        a0 += wA.w * bf2f((uint16_t)v); a1 += wB.w * bf2f((uint16_t)(v >> 16));
    } else {
        uint32_t v;
        if (l >= 2) {
            v = *(const uint32_t*)&xzb[(base + l - 2) * 4096 + d0];
            a0 += wA.y * bf2f((uint16_t)v); a1 += wB.y * bf2f((uint16_t)(v >> 16));
        }
        if (l >= 1) {
            v = *(const uint32_t*)&xzb[(base + l - 1) * 4096 + d0];
            a0 += wA.z * bf2f((uint16_t)v); a1 += wB.z * bf2f((uint16_t)(v >> 16));
        }
        v = *(const uint32_t*)&xzb[(base + l) * 4096 + d0];
        a0 += wA.w * bf2f((uint16_t)v); a1 += wB.w * bf2f((uint16_t)(v >> 16));
    }
    *(uint32_t*)&xsb[(size_t)row * 2048 + d0] = pack2bf(silu_f(a0), silu_f(a1));
}

extern "C" void kernel_launch(void* const* d_in, const int* in_sizes, int n_in,
                              void* d_out, int out_size, void* d_ws, size_t ws_size,
                              hipStream_t stream) {
    const float* x      = (const float*)d_in[0];
    const float* W_in   = (const float*)d_in[1];
    const float* conv_w = (const float*)d_in[2];
    const float* conv_b = (const float*)d_in[3];
    const float* W_x    = (const float*)d_in[4];
    const float* w_dt   = (const float*)d_in[5];
    const float* b_dt   = (const float*)d_in[6];
    const float* A_log  = (const float*)d_in[7];
    const float* Dp     = (const float*)d_in[8];
    const float* W_out  = (const float*)d_in[9];
    float* out = (float*)d_out;

    char* p = (char*)d_ws;
    uint16_t* xb  = (uint16_t*)p;  p += (size_t)NROWS * D_MODEL * 2;      // 8 MB (dead after gemm1)
    uint16_t* Wb  = (uint16_t*)p;  p += (size_t)4096 * 1024 * 2;          // 8 MB (dead after gemm1)
    uint16_t* Wob = (uint16_t*)p;  p += (size_t)1024 * 2048 * 2;          // 4 MB  (W_out^T)
    uint16_t* xzb = (uint16_t*)p;  p += (size_t)NROWS * 4096 * 2;         // 32 MB (bf16 xz; later dtdx)
    uint16_t* xsb = (uint16_t*)p;  p += (size_t)NROWS * D_INNER * 2;      // 16 MB (bf16 xs)
    float* bcd    = (float*)p;     p += (size_t)NROWS * BCD_LD * 4;       // 576 KB
    float* sumdt  = (float*)p;     p += (size_t)NCHUNK * 4096 * 4;        // 1 MB
    float* Wxt    = (float*)p;     p += (size_t)64 * 2048 * 4;            // 512 KB
    uint16_t* ub  = (uint16_t*)p;  p += (size_t)NROWS * D_INNER * 2;      // 16 MB
    uint32_t* szw = (uint32_t*)p;  p += (size_t)NROWS * D_INNER * 4;      // 32 MB (silu(z) pack)
    // overlays (regions dead during their use):
    float* hbuf    = (float*)xb;        // 16 MB = xb+Wb (dead after gemm1)
    float* part    = (float*)ub;        // 12.6 MB (ub written only by kscan3, later)
    uint32_t* dtdx = (uint32_t*)xzb;    // packed (dt, dt*x), in-place over xzb rows

    // 1) fused input prep (cvt + 2 transposes + Wxt)
    kprep0<<<10752, 256, 0, stream>>>(x, xb, W_in, Wb, W_out, Wob, W_x, Wxt);
    // 2) xz = x @ W_in   (M=4096, N=4096, K=1024), bf16 out, 3-buf counted-vmcnt
    kgemm256<1024, 5><<<dim3(32, 16), 512, 0, stream>>>(xb, Wb, xzb, 4096);
    // 3) conv + silu (bf16 in, bf16 out), 2 ch/thread
    kconv<<<NROWS * 1024 / 256, 256, 0, stream>>>(xzb, conv_w, conv_b, xsb);
    // 4) bcd partials = xsb @ W_x  (MFMA, K-split 16, bf16 A)
    kgemm2m<<<dim3(KS2, 32), 256, 0, stream>>>(xsb, Wxt, part);
    // 5) fused reduce + scan-operand packing (dtdx over xzb rows, szw separate)
    kredprep<<<NROWS, 256, 0, stream>>>(part, w_dt, b_dt, Dp, xsb, xzb, szw, bcd);
    // 6) selective scan (3 phases), 1 ch/thread (2048 blocks), tree-decay ILP
    kscan1<<<(4096 * 2 * NCHUNK) / 256, 256, 0, stream>>>(dtdx, bcd, A_log, hbuf, sumdt);
    kscan2<<<(4096 * 16) / 256, 256, 0, stream>>>(hbuf, sumdt, A_log);
    kscan3<<<(4096 * 2 * NCHUNK) / 256, 256, 0, stream>>>(dtdx, bcd, A_log, szw, hbuf, ub);
    // 7) out = u @ W_out (M=4096, N=1024, K=2048), 3-buf counted-vmcnt
    kgemm64<2048, 3><<<dim3(1024 / 128, 4096 / 64), 256, 0, stream>>>(ub, Wob, out, 1024);
}

// Round 19
// 193.924 us; speedup vs baseline: 1.0605x; 1.0334x over previous
//
#include <hip/hip_runtime.h>
#include <hip/hip_bf16.h>
#include <stdint.h>

#define D_MODEL 1024
#define D_STATE 16
#define D_CONV  4
#define D_INNER 2048
#define BATCH   2
#define SEQLEN  2048
#define NROWS   (BATCH*SEQLEN)     // 4096
#define BCD_LD  36                 // padded leading dim for bcd (33 used)
#define NCHUNK  64
#define CHUNKLEN (SEQLEN/NCHUNK)   // 32
#define KS2     16                 // K-splits for GEMM2 (chunk = 128)
#define L2E 1.44269504088896340f

typedef __attribute__((ext_vector_type(8))) short   short8;
typedef __attribute__((ext_vector_type(4))) float   f32x4;

__device__ __forceinline__ uint16_t f2bf(float f) {        // RNE f32->bf16
    uint32_t u = __float_as_uint(f);
    return (uint16_t)((u + 0x7FFFu + ((u >> 16) & 1u)) >> 16);
}
__device__ __forceinline__ float bf2f(uint16_t h) {
    return __uint_as_float(((uint32_t)h) << 16);
}
__device__ __forceinline__ uint32_t pack2bf(float lo, float hi) {
    return (uint32_t)f2bf(lo) | ((uint32_t)f2bf(hi) << 16);
}
__device__ __forceinline__ void gload16(const uint16_t* g, uint16_t* l) {
    __builtin_amdgcn_global_load_lds(
        (const __attribute__((address_space(1))) void*)g,
        (__attribute__((address_space(3))) void*)l, 16, 0, 0);
}
__device__ __forceinline__ void gload16f(const float* g, float* l) {
    __builtin_amdgcn_global_load_lds(
        (const __attribute__((address_space(1))) void*)g,
        (__attribute__((address_space(3))) void*)l, 16, 0, 0);
}
__device__ __forceinline__ float softplus_f(float v) {
    return fmaxf(v, 0.f) + __logf(1.f + __expf(-fabsf(v)));
}
__device__ __forceinline__ float silu_f(float v) {
    return v / (1.f + __expf(-v));
}
__device__ __forceinline__ short8 pack8(const float4 lo, const float4 hi) {
    short8 r;
    r[0] = (short)f2bf(lo.x); r[1] = (short)f2bf(lo.y);
    r[2] = (short)f2bf(lo.z); r[3] = (short)f2bf(lo.w);
    r[4] = (short)f2bf(hi.x); r[5] = (short)f2bf(hi.y);
    r[6] = (short)f2bf(hi.z); r[7] = (short)f2bf(hi.w);
    return r;
}

// ---------- fused input prep: kcvt | ktrans(W_in) | ktrans(W_out) | kwxt ----------
__global__ void kprep0(const float* __restrict__ x, uint16_t* __restrict__ xb,
                       const float* __restrict__ W_in, uint16_t* __restrict__ Wb,
                       const float* __restrict__ W_out, uint16_t* __restrict__ Wob,
                       const float* __restrict__ Wx, float* __restrict__ Wxt) {
    __shared__ float tile[32][33];
    const int blk = blockIdx.x;
    const int tid = threadIdx.x;
    if (blk < 4096) {                          // ---- cvt x -> bf16 (1M float4s)
        const int T = blk * 256 + tid;
        const float4 v = *(const float4*)&x[(size_t)T * 4];
        ushort4 o;
        o.x = f2bf(v.x); o.y = f2bf(v.y); o.z = f2bf(v.z); o.w = f2bf(v.w);
        *(ushort4*)&xb[(size_t)T * 4] = o;
    } else if (blk < 8192) {                   // ---- W_in [1024][4096] -> Wb [4096][1024]
        const int bb = blk - 4096;
        const int n0 = (bb & 127) * 32, k0 = (bb >> 7) * 32;
        const int tx = tid & 31, ty = tid >> 5;
#pragma unroll
        for (int i = 0; i < 4; ++i)
            tile[ty + i * 8][tx] = W_in[(size_t)(k0 + ty + i * 8) * 4096 + n0 + tx];
        __syncthreads();
#pragma unroll
        for (int i = 0; i < 4; ++i)
            Wb[(size_t)(n0 + ty + i * 8) * 1024 + k0 + tx] = f2bf(tile[tx][ty + i * 8]);
    } else if (blk < 10240) {                  // ---- W_out [2048][1024] -> Wob [1024][2048]
        const int bb = blk - 8192;
        const int n0 = (bb & 31) * 32, k0 = (bb >> 5) * 32;
        const int tx = tid & 31, ty = tid >> 5;
#pragma unroll
        for (int i = 0; i < 4; ++i)
            tile[ty + i * 8][tx] = W_out[(size_t)(k0 + ty + i * 8) * 1024 + n0 + tx];
        __syncthreads();
#pragma unroll
        for (int i = 0; i < 4; ++i)
            Wob[(size_t)(n0 + ty + i * 8) * 2048 + k0 + tx] = f2bf(tile[tx][ty + i * 8]);
    } else {                                   // ---- Wxt[64][2048] = W_x^T zero-padded
        const int T = (blk - 10240) * 256 + tid;
        const int j = T >> 11, k = T & 2047;
        Wxt[T] = (j < 33) ? Wx[(size_t)k * 33 + j] : 0.f;
    }
}

// ---------- GEMM1: 256x128 tile, 512 thr, 3-buf counted-vmcnt pipeline ----------
template<int KDIM, int GXL>
__global__ __launch_bounds__(512) void kgemm256(const uint16_t* __restrict__ A,
                                                const uint16_t* __restrict__ B,
                                                uint16_t* __restrict__ C, const int ldc) {
    __shared__ uint16_t As[3][256 * 32];   // 3 x 16 KB
    __shared__ uint16_t Bsh[3][128 * 32];  // 3 x 8 KB  (72 KB total)
    const int t = threadIdx.x;          // 0..511
    const int w = t >> 6, lane = t & 63;
    int wg = blockIdx.y * (1 << GXL) + blockIdx.x;
    wg = (wg & 7) * ((gridDim.x * gridDim.y) >> 3) + (wg >> 3);   // bijective XCD swizzle
    const int m0 = (wg >> GXL) * 256, n0 = (wg & ((1 << GXL) - 1)) * 128;
    const int wm = (w >> 1) * 64, wn = (w & 1) * 64;
    f32x4 acc[4][4] = {};

    const int srow = t >> 2;                              // 0..127
    const int scol = ((t & 3) ^ ((t >> 3) & 3)) * 8;      // pre-swizzled source slot
    const uint16_t* ga0 = A + (size_t)(m0 + srow) * KDIM + scol;
    const uint16_t* ga1 = A + (size_t)(m0 + 128 + srow) * KDIM + scol;
    const uint16_t* gb0 = B + (size_t)(n0 + srow) * KDIM + scol;

    const int fr = lane & 15, fg = (lane >> 4) * 8;
    const int psl = (((fg >> 3) ^ ((fr >> 1) & 3)) << 3);

    auto stage = [&](int buf, int ko) {
        gload16(ga0 + ko, &As[buf][w * 512]);
        gload16(ga1 + ko, &As[buf][4096 + w * 512]);
        gload16(gb0 + ko, &Bsh[buf][w * 512]);
    };

    constexpr int KT = KDIM / 32;
    stage(0, 0);
    stage(1, 32);                       // 6 loads in flight
    int cur = 0;
    for (int kt = 0; kt < KT; ++kt) {
        if (kt + 1 < KT) asm volatile("s_waitcnt vmcnt(3)" ::: "memory");
        else             asm volatile("s_waitcnt vmcnt(0)" ::: "memory");
        asm volatile("s_barrier" ::: "memory");      // all waves' tile-kt loads landed
        if (kt + 2 < KT) stage((kt + 2) % 3, (kt + 2) * 32);
        short8 a[4], b[4];
#pragma unroll
        for (int i = 0; i < 4; ++i) {
            a[i] = *(const short8*)&As[cur][(wm + i * 16 + fr) * 32 + psl];
            b[i] = *(const short8*)&Bsh[cur][(wn + i * 16 + fr) * 32 + psl];
        }
#pragma unroll
        for (int i = 0; i < 4; ++i)
#pragma unroll
            for (int j = 0; j < 4; ++j)
                acc[i][j] = __builtin_amdgcn_mfma_f32_16x16x32_bf16(a[i], b[j], acc[i][j], 0, 0, 0);
        cur = (cur + 1) % 3;
    }
    const int cr = (lane >> 4) * 4, cc = lane & 15;
#pragma unroll
    for (int i = 0; i < 4; ++i)
#pragma unroll
        for (int j = 0; j < 4; ++j)
#pragma unroll
            for (int r = 0; r < 4; ++r)
                C[(size_t)(m0 + wm + i * 16 + cr + r) * ldc + (n0 + wn + j * 16 + cc)] =
                    f2bf(acc[i][j][r]);
}

// ---------- GEMM3: 64x128 tile, BK=64, 3-buf counted-vmcnt (6 loads/tile), f32 C ----------
// LDS tiles [rows][64] bf16 (128B rows, 8x16B slots); swizzle: slot ^= row&7 (involution),
// applied on pre-swizzled global source and on fragment reads.
template<int KDIM, int GXL>
__global__ __launch_bounds__(256) void kgemm64(const uint16_t* __restrict__ A,
                                               const uint16_t* __restrict__ B,
                                               float* __restrict__ C, const int ldc) {
    __shared__ uint16_t As[3][64 * 64];      // 3 x 8 KB
    __shared__ uint16_t Bs[3][128 * 64];     // 3 x 16 KB  (72 KB total)
    const int t = threadIdx.x;               // 0..255
    const int w = t >> 6, lane = t & 63;
    int wg = blockIdx.y * (1 << GXL) + blockIdx.x;
    wg = (wg & 7) * ((gridDim.x * gridDim.y) >> 3) + (wg >> 3);
    const int m0 = (wg >> GXL) * 64, n0 = (wg & ((1 << GXL) - 1)) * 128;
    const int wm = (w >> 1) * 32, wn = (w & 1) * 64;
    f32x4 acc[2][4] = {};

    // staging maps: idx = l*256 + t -> row = idx>>3, slot = idx&7 (16B slots)
    // A half: 2 loads (64 rows); B: 4 loads (128 rows)
    int arow[2], acol[2];
#pragma unroll
    for (int l = 0; l < 2; ++l) {
        const int idx = l * 256 + t;
        arow[l] = idx >> 3;
        acol[l] = ((idx & 7) ^ (arow[l] & 7)) * 8;     // pre-swizzled source elems
    }
    int brow[4], bcol[4];
#pragma unroll
    for (int l = 0; l < 4; ++l) {
        const int idx = l * 256 + t;
        brow[l] = idx >> 3;
        bcol[l] = ((idx & 7) ^ (brow[l] & 7)) * 8;
    }
    const uint16_t* gaA0 = A + (size_t)(m0 + arow[0]) * KDIM + acol[0];
    const uint16_t* gaA1 = A + (size_t)(m0 + arow[1]) * KDIM + acol[1];
    const uint16_t* gbB0 = B + (size_t)(n0 + brow[0]) * KDIM + bcol[0];
    const uint16_t* gbB1 = B + (size_t)(n0 + brow[1]) * KDIM + bcol[1];
    const uint16_t* gbB2 = B + (size_t)(n0 + brow[2]) * KDIM + bcol[2];
    const uint16_t* gbB3 = B + (size_t)(n0 + brow[3]) * KDIM + bcol[3];

    auto stage = [&](int buf, int ko) {
        gload16(gaA0 + ko, &As[buf][(0 * 256 + w * 64) * 8]);
        gload16(gaA1 + ko, &As[buf][(1 * 256 + w * 64) * 8]);
        gload16(gbB0 + ko, &Bs[buf][(0 * 256 + w * 64) * 8]);
        gload16(gbB1 + ko, &Bs[buf][(1 * 256 + w * 64) * 8]);
        gload16(gbB2 + ko, &Bs[buf][(2 * 256 + w * 64) * 8]);
        gload16(gbB3 + ko, &Bs[buf][(3 * 256 + w * 64) * 8]);
    };

    const int fr = lane & 15, lg = lane >> 4;           // lane group 0..3
    constexpr int KT = KDIM / 64;                       // 32 K-tiles
    stage(0, 0);
    stage(1, 64);                       // 12 loads in flight
    int cur = 0;
    for (int kt = 0; kt < KT; ++kt) {
        if (kt + 1 < KT) asm volatile("s_waitcnt vmcnt(6)" ::: "memory");
        else             asm volatile("s_waitcnt vmcnt(0)" ::: "memory");
        asm volatile("s_barrier" ::: "memory");      // buffer kt fully landed block-wide
        if (kt + 2 < KT) stage((kt + 2) % 3, (kt + 2) * 64);
        short8 a[2][2], b[4][2];
#pragma unroll
        for (int ks = 0; ks < 2; ++ks) {
#pragma unroll
            for (int i = 0; i < 2; ++i) {
                const int R = wm + i * 16 + fr;
                const int phys = ((ks * 4 + lg) ^ (R & 7)) * 8;
                a[i][ks] = *(const short8*)&As[cur][R * 64 + phys];
            }
#pragma unroll
            for (int j = 0; j < 4; ++j) {
                const int R = wn + j * 16 + fr;
                const int phys = ((ks * 4 + lg) ^ (R & 7)) * 8;
                b[j][ks] = *(const short8*)&Bs[cur][R * 64 + phys];
            }
        }
#pragma unroll
        for (int ks = 0; ks < 2; ++ks)
#pragma unroll
            for (int i = 0; i < 2; ++i)
#pragma unroll
                for (int j = 0; j < 4; ++j)
                    acc[i][j] = __builtin_amdgcn_mfma_f32_16x16x32_bf16(a[i][ks], b[j][ks],
                                                                        acc[i][j], 0, 0, 0);
        cur = (cur + 1) % 3;
    }
    const int cr = lg * 4, cc = fr;
#pragma unroll
    for (int i = 0; i < 2; ++i)
#pragma unroll
        for (int j = 0; j < 4; ++j)
#pragma unroll
            for (int r = 0; r < 4; ++r)
                C[(size_t)(m0 + wm + i * 16 + cr + r) * ldc + (n0 + wn + j * 16 + cc)] = acc[i][j][r];
}

// ---------- GEMM2 MFMA K-split: part[kb][4096][48] = xsb(chunk) @ Wxt^T ----------
__global__ __launch_bounds__(256) void kgemm2m(const uint16_t* __restrict__ xsb,
        const float* __restrict__ Wxt, float* __restrict__ part) {
    __shared__ uint16_t As[128 * 32];   // 8 KB bf16
    __shared__ float Bs[64 * 32];       // 8 KB f32
    const int t = threadIdx.x;
    const int w = t >> 6, lane = t & 63;
    const int kb = blockIdx.x;              // 0..15
    const int m0 = blockIdx.y * 128;
    const int kc = kb * 128;
    f32x4 acc[2][3] = {};

    const int srowA = t >> 2;                             // 0..63
    const int scolA = ((t & 3) ^ ((t >> 3) & 3)) * 8;     // elems
    const uint16_t* ga0 = xsb + (size_t)(m0 + srowA) * 2048 + scolA;
    const uint16_t* ga1 = xsb + (size_t)(m0 + 64 + srowA) * 2048 + scolA;
    uint16_t* lA0 = &As[w * 512];
    uint16_t* lA1 = &As[2048 + w * 512];

    const int srowB = t >> 3;                            // 0..31
    const int scolB = ((t & 7) ^ ((t >> 3) & 7)) * 4;    // floats
    float* lB[2];
#pragma unroll
    for (int r = 0; r < 2; ++r) lB[r] = &Bs[(r * 32 + w * 8) * 32];

    const int wm = w * 32;
    const int fr = lane & 15, fg = (lane >> 4) * 8;
    const int psl = (((fg >> 3) ^ ((fr >> 1) & 3)) << 3);   // bf16 A read slot
    const int plo = (((fg >> 2) ^ (fr & 7))) * 4;           // f32 B read slots
    const int phi = ((((fg >> 2) + 1) ^ (fr & 7))) * 4;

    for (int kt = 0; kt < 4; ++kt) {
        const int ko = kc + kt * 32;
        gload16(ga0 + ko, lA0);
        gload16(ga1 + ko, lA1);
#pragma unroll
        for (int r = 0; r < 2; ++r)
            gload16f(Wxt + (size_t)(r * 32 + srowB) * 2048 + ko + scolB, lB[r]);
        __syncthreads();
        short8 a[2], b[3];
#pragma unroll
        for (int i = 0; i < 2; ++i)
            a[i] = *(const short8*)&As[(wm + i * 16 + fr) * 32 + psl];
#pragma unroll
        for (int j = 0; j < 3; ++j) {
            const float* base = &Bs[(j * 16 + fr) * 32];
            b[j] = pack8(*(const float4*)&base[plo], *(const float4*)&base[phi]);
        }
#pragma unroll
        for (int i = 0; i < 2; ++i)
#pragma unroll
            for (int j = 0; j < 3; ++j)
                acc[i][j] = __builtin_amdgcn_mfma_f32_16x16x32_bf16(a[i], b[j], acc[i][j], 0, 0, 0);
        __syncthreads();
    }
    const int cr = (lane >> 4) * 4, cc = lane & 15;
    float* pb = part + (size_t)kb * 4096 * 48;
#pragma unroll
    for (int i = 0; i < 2; ++i)
#pragma unroll
        for (int j = 0; j < 3; ++j)
#pragma unroll
            for (int r = 0; r < 4; ++r)
                pb[(size_t)(m0 + wm + i * 16 + cr + r) * 48 + j * 16 + cc] = acc[i][j][r];
}

// ---------- fused: reduce partials -> bcd row; pack dtdx (over xzb row) + szw ----------
__global__ __launch_bounds__(256) void kredprep(const float* __restrict__ part,
        const float* __restrict__ wdt, const float* __restrict__ bdt,
        const float* __restrict__ Dp, const uint16_t* __restrict__ xsb,
        uint16_t* __restrict__ xzb_io, uint32_t* __restrict__ szw,
        float* __restrict__ bcd) {
    const int row = blockIdx.x;
    const int t = threadIdx.x;
    __shared__ float rawsh;
    if (t < 33) {
        float s = 0.f;
#pragma unroll
        for (int ks = 0; ks < KS2; ++ks)
            s += part[(size_t)ks * 4096 * 48 + (size_t)row * 48 + t];
        bcd[(size_t)row * BCD_LD + t] = s;
        if (t == 32) rawsh = s;
    }
    __syncthreads();
    const float raw = rawsh;
    ushort4 xu[2], zu[2];
#pragma unroll
    for (int g = 0; g < 2; ++g) {
        const int dg = t * 8 + g * 4;
        xu[g] = *(const ushort4*)&xsb[(size_t)row * 2048 + dg];
        zu[g] = *(const ushort4*)&xzb_io[(size_t)row * 4096 + 2048 + dg];
    }
    __syncthreads();          // all z reads done block-wide before row overwrite
    uint32_t* dtdx = (uint32_t*)xzb_io;
#pragma unroll
    for (int g = 0; g < 2; ++g) {
        const int dg = t * 8 + g * 4;
        const float4 w  = *(const float4*)&wdt[dg];
        const float4 b  = *(const float4*)&bdt[dg];
        const float4 Dv = *(const float4*)&Dp[dg];
        const float x0 = bf2f(xu[g].x), x1 = bf2f(xu[g].y);
        const float x2 = bf2f(xu[g].z), x3 = bf2f(xu[g].w);
        const float dt0 = softplus_f(raw * w.x + b.x);
        const float dt1 = softplus_f(raw * w.y + b.y);
        const float dt2 = softplus_f(raw * w.z + b.z);
        const float dt3 = softplus_f(raw * w.w + b.w);
        uint4 pd;
        pd.x = pack2bf(dt0, dt0 * x0);
        pd.y = pack2bf(dt1, dt1 * x1);
        pd.z = pack2bf(dt2, dt2 * x2);
        pd.w = pack2bf(dt3, dt3 * x3);
        const float s0 = silu_f(bf2f(zu[g].x)), s1 = silu_f(bf2f(zu[g].y));
        const float s2 = silu_f(bf2f(zu[g].z)), s3 = silu_f(bf2f(zu[g].w));
        uint4 ps;
        ps.x = pack2bf(s0, x0 * Dv.x * s0);
        ps.y = pack2bf(s1, x1 * Dv.y * s1);
        ps.z = pack2bf(s2, x2 * Dv.z * s2);
        ps.w = pack2bf(s3, x3 * Dv.w * s3);
        *(uint4*)&dtdx[(size_t)row * 2048 + dg] = pd;
        *(uint4*)&szw[(size_t)row * 2048 + dg] = ps;
    }
}

// ---------- scan phase 1: 1 ch/thread (2 lanes/ch, 8 states each), full occupancy ----------
__global__ __launch_bounds__(256) void kscan1(const uint32_t* __restrict__ dtdx,
        const float* __restrict__ bcd, const float* __restrict__ Alog,
        float* __restrict__ hbuf, float* __restrict__ sumdt) {
    const int T = blockIdx.x * 256 + threadIdx.x;
    const int sub = T & 1;
    const int ch  = (T >> 1) & 4095;
    const int chunk = T >> 13;
    const int b = ch >> 11, d = ch & 2047;
    const int row0 = b * SEQLEN + chunk * CHUNKLEN;    // uniform per block

    __shared__ float Bls[32][16];       // B part (cols 0..15) of the 32 chunk rows
    {
        const int r = threadIdx.x >> 3, c = (threadIdx.x & 7) * 2;
        const float2 v = *(const float2*)&bcd[(size_t)(row0 + r) * BCD_LD + c];
        Bls[r][c] = v.x; Bls[r][c + 1] = v.y;
    }
    __syncthreads();

    float Ae[8]; bool st = true;
#pragma unroll
    for (int i = 0; i < 8; ++i) {
        const float a0 = __expf(Alog[d * 16 + sub * 8 + i]);
        Ae[i] = -a0 * L2E;
        st = st && (fabsf(a0 - (float)(sub * 8 + i + 1)) < 1e-3f);
    }
    float h[8] = {};
    float sdt = 0.f;
    const uint32_t* pD = dtdx + (size_t)row0 * 2048 + d;
    if (st) {
        for (int l0 = 0; l0 < CHUNKLEN; l0 += 4) {
            uint32_t pk[4];
#pragma unroll
            for (int s = 0; s < 4; ++s) pk[s] = pD[(size_t)s * 2048];
#pragma unroll
            for (int s = 0; s < 4; ++s) {
                const float4 B0 = *(const float4*)&Bls[l0 + s][sub * 8];
                const float4 B1 = *(const float4*)&Bls[l0 + s][sub * 8 + 4];
                const float dt  = __uint_as_float(pk[s] << 16);
                const float dtx = __uint_as_float(pk[s] & 0xffff0000u);
                sdt += dt;
                const float e0 = __builtin_amdgcn_exp2f(dt * (-L2E));
                const float e2 = e0 * e0, e4 = e2 * e2;
                const float bs = sub ? (e4 * e4) : 1.f;
                const float d0 = bs * e0, d1 = bs * e2;
                const float d2 = d1 * e0, d3 = d1 * e2;
                const float d4 = d3 * e0, d5 = d3 * e2;
                const float d6 = d5 * e0, d7 = d5 * e2;
                h[0] = fmaf(d0, h[0], dtx * B0.x);
                h[1] = fmaf(d1, h[1], dtx * B0.y);
                h[2] = fmaf(d2, h[2], dtx * B0.z);
                h[3] = fmaf(d3, h[3], dtx * B0.w);
                h[4] = fmaf(d4, h[4], dtx * B1.x);
                h[5] = fmaf(d5, h[5], dtx * B1.y);
                h[6] = fmaf(d6, h[6], dtx * B1.z);
                h[7] = fmaf(d7, h[7], dtx * B1.w);
            }
            pD += 4 * 2048;
        }
    } else {
        for (int l0 = 0; l0 < CHUNKLEN; l0 += 4) {
            uint32_t pk[4];
#pragma unroll
            for (int s = 0; s < 4; ++s) pk[s] = pD[(size_t)s * 2048];
#pragma unroll
            for (int s = 0; s < 4; ++s) {
                const float4 B0 = *(const float4*)&Bls[l0 + s][sub * 8];
                const float4 B1 = *(const float4*)&Bls[l0 + s][sub * 8 + 4];
                const float dt  = __uint_as_float(pk[s] << 16);
                const float dtx = __uint_as_float(pk[s] & 0xffff0000u);
                sdt += dt;
                const float Bv[8] = {B0.x, B0.y, B0.z, B0.w, B1.x, B1.y, B1.z, B1.w};
#pragma unroll
                for (int i = 0; i < 8; ++i)
                    h[i] = fmaf(__builtin_amdgcn_exp2f(dt * Ae[i]), h[i], dtx * Bv[i]);
            }
            pD += 4 * 2048;
        }
    }
    const size_t cc0 = (size_t)(chunk * 4096 + ch) * 16 + sub * 8;
    *(float4*)&hbuf[cc0]     = make_float4(h[0], h[1], h[2], h[3]);
    *(float4*)&hbuf[cc0 + 4] = make_float4(h[4], h[5], h[6], h[7]);
    if (sub == 0) sumdt[chunk * 4096 + ch] = sdt;
}

// ---------- scan phase 2: chunk combine (in-place carries), next-iter prefetch ----------
__global__ void kscan2(float* __restrict__ hbuf, const float* __restrict__ sumdt,
                       const float* __restrict__ Alog) {
    const int T = blockIdx.x * 256 + threadIdx.x;   // 65536
    const int n = T & 15, ch = T >> 4;
    const int d = ch & 2047;
    const float Ae = -__expf(Alog[d * 16 + n]) * L2E;
    float h = 0.f;
    size_t idx = (size_t)ch * 16 + n;
    float loc = hbuf[idx];
    float sd  = sumdt[ch];
    for (int c = 0; c < NCHUNK; ++c) {
        float locN = 0.f, sdN = 0.f;
        const size_t idxN = idx + (size_t)4096 * 16;
        if (c + 1 < NCHUNK) {
            locN = hbuf[idxN];
            sdN  = sumdt[(size_t)(c + 1) * 4096 + ch];
        }
        hbuf[idx] = h;
        h = __builtin_amdgcn_exp2f(Ae * sd) * h + loc;
        loc = locN; sd = sdN; idx = idxN;
    }
}

// ---------- scan phase 3: 1 ch/thread, bcd B+C in LDS, full occupancy ----------
__global__ __launch_bounds__(256) void kscan3(const uint32_t* __restrict__ dtdx,
        const float* __restrict__ bcd, const float* __restrict__ Alog,
        const uint32_t* __restrict__ szw, const float* __restrict__ hbuf,
        uint16_t* __restrict__ u) {
    const int T = blockIdx.x * 256 + threadIdx.x;
    const int sub = T & 1;
    const int ch  = (T >> 1) & 4095;
    const int chunk = T >> 13;
    const int b = ch >> 11, d = ch & 2047;
    const int row0 = b * SEQLEN + chunk * CHUNKLEN;    // uniform per block

    __shared__ float BC[32][32];        // B (0..15) + C (16..31) of the 32 chunk rows
    {
        const int r = threadIdx.x >> 3, c = (threadIdx.x & 7) * 4;
        *(float4*)&BC[r][c] = *(const float4*)&bcd[(size_t)(row0 + r) * BCD_LD + c];
    }
    __syncthreads();

    float Ae[8]; bool st = true;
#pragma unroll
    for (int i = 0; i < 8; ++i) {
        const float a0 = __expf(Alog[d * 16 + sub * 8 + i]);
        Ae[i] = -a0 * L2E;
        st = st && (fabsf(a0 - (float)(sub * 8 + i + 1)) < 1e-3f);
    }
    float h[8];
    {
        const size_t cc0 = (size_t)(chunk * 4096 + ch) * 16 + sub * 8;
        const float4 a0 = *(const float4*)&hbuf[cc0];
        const float4 a1 = *(const float4*)&hbuf[cc0 + 4];
        h[0]=a0.x; h[1]=a0.y; h[2]=a0.z; h[3]=a0.w;
        h[4]=a1.x; h[5]=a1.y; h[6]=a1.z; h[7]=a1.w;
    }
    const uint32_t* pD = dtdx + (size_t)row0 * 2048 + d;
    const uint32_t* pS = szw  + (size_t)row0 * 2048 + d;   // only sub==0 reads
    uint16_t* pU = u + (size_t)row0 * D_INNER + d;
    if (st) {
        for (int l0 = 0; l0 < CHUNKLEN; l0 += 4) {
            uint32_t pk[4], qk[4];
#pragma unroll
            for (int s = 0; s < 4; ++s) {
                pk[s] = pD[(size_t)s * 2048];
                if (sub == 0) qk[s] = pS[(size_t)s * 2048];
            }
#pragma unroll
            for (int s = 0; s < 4; ++s) {
                const float4 B0 = *(const float4*)&BC[l0 + s][sub * 8];
                const float4 B1 = *(const float4*)&BC[l0 + s][sub * 8 + 4];
                const float4 C0 = *(const float4*)&BC[l0 + s][16 + sub * 8];
                const float4 C1 = *(const float4*)&BC[l0 + s][20 + sub * 8];
                const float dt  = __uint_as_float(pk[s] << 16);
                const float dtx = __uint_as_float(pk[s] & 0xffff0000u);
                const float e0 = __builtin_amdgcn_exp2f(dt * (-L2E));
                const float e2 = e0 * e0, e4 = e2 * e2;
                const float bs = sub ? (e4 * e4) : 1.f;
                const float d0 = bs * e0, d1 = bs * e2;
                const float d2 = d1 * e0, d3 = d1 * e2;
                const float d4 = d3 * e0, d5 = d3 * e2;
                const float d6 = d5 * e0, d7 = d5 * e2;
                h[0] = fmaf(d0, h[0], dtx * B0.x);
                h[1] = fmaf(d1, h[1], dtx * B0.y);
                h[2] = fmaf(d2, h[2], dtx * B0.z);
                h[3] = fmaf(d3, h[3], dtx * B0.w);
                h[4] = fmaf(d4, h[4], dtx * B1.x);
                h[5] = fmaf(d5, h[5], dtx * B1.y);
                h[6] = fmaf(d6, h[6], dtx * B1.z);
                h[7] = fmaf(d7, h[7], dtx * B1.w);
                float y = ((h[0]*C0.x + h[1]*C0.y) + (h[2]*C0.z + h[3]*C0.w))
                        + ((h[4]*C1.x + h[5]*C1.y) + (h[6]*C1.z + h[7]*C1.w));
                y += __shfl_xor(y, 1);
                if (sub == 0) {
                    const float sz = __uint_as_float(qk[s] << 16);
                    const float w2 = __uint_as_float(qk[s] & 0xffff0000u);
                    pU[(size_t)s * D_INNER] = f2bf(fmaf(y, sz, w2));
                }
            }
            pD += 4 * 2048; pS += 4 * 2048; pU += 4 * D_INNER;
        }
    } else {
        for (int l0 = 0; l0 < CHUNKLEN; l0 += 4) {
            uint32_t pk[4], qk[4];
#pragma unroll
            for (int s = 0; s < 4; ++s) {
                pk[s] = pD[(size_t)s * 2048];
                if (sub == 0) qk[s] = pS[(size_t)s * 2048];
            }
#pragma unroll
            for (int s = 0; s < 4; ++s) {
                const float4 B0 = *(const float4*)&BC[l0 + s][sub * 8];
                const float4 B1 = *(const float4*)&BC[l0 + s][sub * 8 + 4];
                const float4 C0 = *(const float4*)&BC[l0 + s][16 + sub * 8];
                const float4 C1 = *(const float4*)&BC[l0 + s][20 + sub * 8];
                const float dt  = __uint_as_float(pk[s] << 16);
                const float dtx = __uint_as_float(pk[s] & 0xffff0000u);
                const float Bv[8] = {B0.x, B0.y, B0.z, B0.w, B1.x, B1.y, B1.z, B1.w};
                const float Cv[8] = {C0.x, C0.y, C0.z, C0.w, C1.x, C1.y, C1.z, C1.w};
                float y = 0.f;
#pragma unroll
                for (int i = 0; i < 8; ++i) {
                    h[i] = fmaf(__builtin_amdgcn_exp2f(dt * Ae[i]), h[i], dtx * Bv[i]);
                    y = fmaf(h[i], Cv[i], y);
                }
                y += __shfl_xor(y, 1);
                if (sub == 0) {
                    const float sz = __uint_as_float(qk[s] << 16);
                    const float w2 = __uint_as_float(qk[s] & 0xffff0000u);
                    pU[(size_t)s * D_INNER] = f2bf(fmaf(y, sz, w2));
                }
            }
            pD += 4 * 2048; pS += 4 * 2048; pU += 4 * D_INNER;
        }
    }
}

// ---------- causal depthwise conv (k=4) + bias + SiLU, 2 ch/thread, bf16 out ----------
__global__ void kconv(const uint16_t* __restrict__ xzb, const float* __restrict__ cw,
                      const float* __restrict__ cb, uint16_t* __restrict__ xsb) {
    const int T = blockIdx.x * 256 + threadIdx.x;   // over NROWS*1024
    const int d0 = (T & 1023) * 2;
    const int row = T >> 10;
    const int l = row & (SEQLEN - 1), b = row >> 11;
    const float4 wA = *(const float4*)&cw[d0 * 4];
    const float4 wB = *(const float4*)&cw[d0 * 4 + 4];
    const float2 bias = *(const float2*)&cb[d0];
    float a0 = bias.x, a1 = bias.y;
    const size_t base = (size_t)b * SEQLEN;
    if (l >= 3) {
        uint32_t v;
        v = *(const uint32_t*)&xzb[(base + l - 3) * 4096 + d0];
        a0 += wA.x * bf2f((uint16_t)v); a1 += wB.x * bf2f((uint16_t)(v >> 16));
        v = *(const uint32_t*)&xzb[(base + l - 2) * 4096 + d0];
        a0 += wA.y * bf2f((uint16_t)v); a1 += wB.y * bf2f((uint16_t)(v >> 16));
        v = *(const uint32_t*)&xzb[(base + l - 1) * 4096 + d0];
        a0 += wA.z * bf2f((uint16_t)v); a1 += wB.z * bf2f((uint16_t)(v >> 16));
        v = *(const uint32_t*)&xzb[(base + l    ) * 4096 + d0];
        a0 += wA.w * bf2f((uint16_t)v); a1 += wB.w * bf2f((uint16_t)(v >> 16));
    } else {
        uint32_t v;
        if (l >= 2) {
            v = *(const uint32_t*)&xzb[(base + l - 2) * 4096 + d0];
            a0 += wA.y * bf2f((uint16_t)v); a1 += wB.y * bf2f((uint16_t)(v >> 16));
        }
        if (l >= 1) {
            v = *(const uint32_t*)&xzb[(base + l - 1) * 4096 + d0];
            a0 += wA.z * bf2f((uint16_t)v); a1 += wB.z * bf2f((uint16_t)(v >> 16));
        }
        v = *(const uint32_t*)&xzb[(base + l) * 4096 + d0];
        a0 += wA.w * bf2f((uint16_t)v); a1 += wB.w * bf2f((uint16_t)(v >> 16));
    }
    *(uint32_t*)&xsb[(size_t)row * 2048 + d0] = pack2bf(silu_f(a0), silu_f(a1));
}

extern "C" void kernel_launch(void* const* d_in, const int* in_sizes, int n_in,
                              void* d_out, int out_size, void* d_ws, size_t ws_size,
                              hipStream_t stream) {
    const float* x      = (const float*)d_in[0];
    const float* W_in   = (const float*)d_in[1];
    const float* conv_w = (const float*)d_in[2];
    const float* conv_b = (const float*)d_in[3];
    const float* W_x    = (const float*)d_in[4];
    const float* w_dt   = (const float*)d_in[5];
    const float* b_dt   = (const float*)d_in[6];
    const float* A_log  = (const float*)d_in[7];
    const float* Dp     = (const float*)d_in[8];
    const float* W_out  = (const float*)d_in[9];
    float* out = (float*)d_out;

    char* p = (char*)d_ws;
    uint16_t* xb  = (uint16_t*)p;  p += (size_t)NROWS * D_MODEL * 2;      // 8 MB (dead after gemm1)
    uint16_t* Wb  = (uint16_t*)p;  p += (size_t)4096 * 1024 * 2;          // 8 MB (dead after gemm1)
    uint16_t* Wob = (uint16_t*)p;  p += (size_t)1024 * 2048 * 2;          // 4 MB  (W_out^T)
    uint16_t* xzb = (uint16_t*)p;  p += (size_t)NROWS * 4096 * 2;         // 32 MB (bf16 xz; later dtdx)
    uint16_t* xsb = (uint16_t*)p;  p += (size_t)NROWS * D_INNER * 2;      // 16 MB (bf16 xs)
    float* bcd    = (float*)p;     p += (size_t)NROWS * BCD_LD * 4;       // 576 KB
    float* sumdt  = (float*)p;     p += (size_t)NCHUNK * 4096 * 4;        // 1 MB
    float* Wxt    = (float*)p;     p += (size_t)64 * 2048 * 4;            // 512 KB
    uint16_t* ub  = (uint16_t*)p;  p += (size_t)NROWS * D_INNER * 2;      // 16 MB
    uint32_t* szw = (uint32_t*)p;  p += (size_t)NROWS * D_INNER * 4;      // 32 MB (silu(z) pack)
    // overlays (regions dead during their use):
    float* hbuf    = (float*)xb;        // 16 MB = xb+Wb (dead after gemm1)
    float* part    = (float*)ub;        // 12.6 MB (ub written only by kscan3, later)
    uint32_t* dtdx = (uint32_t*)xzb;    // packed (dt, dt*x), in-place over xzb rows

    // 1) fused input prep (cvt + 2 transposes + Wxt)
    kprep0<<<10752, 256, 0, stream>>>(x, xb, W_in, Wb, W_out, Wob, W_x, Wxt);
    // 2) xz = x @ W_in   (M=4096, N=4096, K=1024), bf16 out, 3-buf counted-vmcnt
    kgemm256<1024, 5><<<dim3(32, 16), 512, 0, stream>>>(xb, Wb, xzb, 4096);
    // 3) conv + silu (bf16 in, bf16 out), 2 ch/thread
    kconv<<<NROWS * 1024 / 256, 256, 0, stream>>>(xzb, conv_w, conv_b, xsb);
    // 4) bcd partials = xsb @ W_x  (MFMA, K-split 16, bf16 A)
    kgemm2m<<<dim3(KS2, 32), 256, 0, stream>>>(xsb, Wxt, part);
    // 5) fused reduce + scan-operand packing (dtdx over xzb rows, szw separate)
    kredprep<<<NROWS, 256, 0, stream>>>(part, w_dt, b_dt, Dp, xsb, xzb, szw, bcd);
    // 6) selective scan (3 phases), 1 ch/thread (2048 blocks), tree-decay ILP
    kscan1<<<(4096 * 2 * NCHUNK) / 256, 256, 0, stream>>>(dtdx, bcd, A_log, hbuf, sumdt);
    kscan2<<<(4096 * 16) / 256, 256, 0, stream>>>(hbuf, sumdt, A_log);
    kscan3<<<(4096 * 2 * NCHUNK) / 256, 256, 0, stream>>>(dtdx, bcd, A_log, szw, hbuf, ub);
    // 7) out = u @ W_out (M=4096, N=1024, K=2048), BK=64 3-buf counted-vmcnt
    kgemm64<2048, 3><<<dim3(1024 / 128, 4096 / 64), 256, 0, stream>>>(ub, Wob, out, 1024);
}